// Round 3
// baseline (107.875 us; speedup 1.0000x reference)
//
#include <hip/hip_runtime.h>
#include <hip/hip_bf16.h>

#define NB 32
#define NSEQ 3136
#define NDIM 64
#define NH 8
#define NAG 49

static constexpr float kScale = 0.35355339059327378f; // 8^-0.5
static constexpr float kLog2e = 1.4426950408889634f;

typedef unsigned short us;
typedef __attribute__((ext_vector_type(8))) __bf16 bf16x8;
typedef __attribute__((ext_vector_type(4))) __bf16 bf16x4;
typedef __attribute__((ext_vector_type(2))) _Float16 f16x2;
typedef __attribute__((ext_vector_type(4))) _Float16 f16x4;
typedef __attribute__((ext_vector_type(4))) float f32x4;
typedef __attribute__((ext_vector_type(2))) float f32x2;

__device__ __forceinline__ f32x2 up2(unsigned int u) { // {lo,hi} bf16 pair -> f32x2
  return (f32x2){__uint_as_float(u << 16), __uint_as_float(u & 0xffff0000u)};
}

__device__ __forceinline__ float fexp2(float x) {
#if __has_builtin(__builtin_amdgcn_exp2f)
  return __builtin_amdgcn_exp2f(x);
#else
  return exp2f(x);
#endif
}

// ---------------------------------------------------------------------------
// Kernel P: convert Wq,Wk,Wv (64x64) and Wo (128x128) to bf16; zero pvs.
// ---------------------------------------------------------------------------
__global__ __launch_bounds__(256) void prep_kernel(
    const float* __restrict__ Wq, const float* __restrict__ Wk,
    const float* __restrict__ Wv, const float* __restrict__ Wo,
    __bf16* __restrict__ wq, __bf16* __restrict__ wk, __bf16* __restrict__ wv,
    __bf16* __restrict__ wo, float* __restrict__ pvs) {
  int i = blockIdx.x * 256 + threadIdx.x; // 64 blocks -> 16384
  wo[i] = (__bf16)Wo[i];
  if (i < 4096) { wq[i] = (__bf16)Wq[i]; wk[i] = (__bf16)Wk[i]; wv[i] = (__bf16)Wv[i]; }
  for (int j = i; j < NB * NH * NAG * 12; j += 16384) pvs[j] = 0.f;
}

// ---------------------------------------------------------------------------
// Kernel A: kv^T GEMM via swapped MFMA operands (C = W @ x2^T) so each lane
// holds 4 consecutive FEATURES of one token -> direct f16 global stores, no
// LDS transpose. agent = log2e * kScale * (colsum(x1)/64) @ Wq^T in f32.
// kvh[b,h,j][0..7]=k f16, [8..15]=v f16. grid (49,32), block 256 (4 waves).
// ---------------------------------------------------------------------------
__global__ __launch_bounds__(256, 4) void qkv_agent_kernel(
    const float* __restrict__ x1, const float* __restrict__ x2,
    const float* __restrict__ Wq, const __bf16* __restrict__ wk,
    const __bf16* __restrict__ wv, us* __restrict__ kvh,
    float* __restrict__ agent) {
  __shared__ __align__(16) __bf16 xb[64][72];
  __shared__ __align__(16) float red[4][64];
  __shared__ __align__(16) float marr[64];
  const int a = blockIdx.x, b = blockIdx.y, t = threadIdx.x;
  const int i64 = t & 63, cb = t >> 6;
  const int w = cb, lr = (t >> 4) & 3, lc = t & 15;

  // prefetch A-frags (W rows; independent of LDS, overlaps staging)
  bf16x8 ak0 = *(const bf16x8*)(wk + (size_t)(w * 16 + lc) * NDIM + lr * 8);
  bf16x8 ak1 = *(const bf16x8*)(wk + (size_t)(w * 16 + lc) * NDIM + 32 + lr * 8);
  bf16x8 av0 = *(const bf16x8*)(wv + (size_t)(w * 16 + lc) * NDIM + lr * 8);
  bf16x8 av1 = *(const bf16x8*)(wv + (size_t)(w * 16 + lc) * NDIM + 32 + lr * 8);

  // stage x2 tile as bf16 (thread: one row, 16 cols)
  {
    const float4* s2 = (const float4*)(x2 + ((size_t)(b * NSEQ) + a * 64 + i64) * NDIM + cb * 16);
    float4 v0 = s2[0], v1 = s2[1], v2 = s2[2], v3 = s2[3];
    bf16x8 p0, p1;
    p0[0]=(__bf16)v0.x; p0[1]=(__bf16)v0.y; p0[2]=(__bf16)v0.z; p0[3]=(__bf16)v0.w;
    p0[4]=(__bf16)v1.x; p0[5]=(__bf16)v1.y; p0[6]=(__bf16)v1.z; p0[7]=(__bf16)v1.w;
    p1[0]=(__bf16)v2.x; p1[1]=(__bf16)v2.y; p1[2]=(__bf16)v2.z; p1[3]=(__bf16)v2.w;
    p1[4]=(__bf16)v3.x; p1[5]=(__bf16)v3.y; p1[6]=(__bf16)v3.z; p1[7]=(__bf16)v3.w;
    *(bf16x8*)&xb[i64][cb * 16] = p0; *(bf16x8*)&xb[i64][cb * 16 + 8] = p1;
  }
  // x1 column partial sums (wave reads are fully coalesced: 64 lanes = 64 cols)
  {
    const float* xc = x1 + ((size_t)(b * NSEQ) + a * 64 + cb * 16) * NDIM + i64;
    float cs = 0.f;
#pragma unroll
    for (int i = 0; i < 16; ++i) cs += xc[i * NDIM];
    red[cb][i64] = cs;
  }
  __syncthreads();

  // kv^T GEMM: wave w covers k-feats [w*16,w*16+16) and v-feats likewise.
  f32x4 acck[4], accv[4];
#pragma unroll
  for (int i = 0; i < 4; ++i) {
    acck[i] = (f32x4){0.f, 0.f, 0.f, 0.f};
    accv[i] = (f32x4){0.f, 0.f, 0.f, 0.f};
  }
#pragma unroll
  for (int nt = 0; nt < 4; ++nt) {
    bf16x8 x0 = *(const bf16x8*)&xb[nt * 16 + lc][lr * 8];
    bf16x8 x1f = *(const bf16x8*)&xb[nt * 16 + lc][32 + lr * 8];
    acck[nt] = __builtin_amdgcn_mfma_f32_16x16x32_bf16(ak0, x0, acck[nt], 0, 0, 0);
    acck[nt] = __builtin_amdgcn_mfma_f32_16x16x32_bf16(ak1, x1f, acck[nt], 0, 0, 0);
    accv[nt] = __builtin_amdgcn_mfma_f32_16x16x32_bf16(av0, x0, accv[nt], 0, 0, 0);
    accv[nt] = __builtin_amdgcn_mfma_f32_16x16x32_bf16(av1, x1f, accv[nt], 0, 0, 0);
  }
  // C layout: row = feat = lr*4+j (within wave's 16), col = tok = nt*16+lc.
  // feat f = w*16+lr*4+j -> head = f>>3 = 2w + (lr>>1), slot = (lr&1)*4 + j.
  const int head = 2 * w + (lr >> 1), sb = (lr & 1) * 4;
#pragma unroll
  for (int nt = 0; nt < 4; ++nt) {
    _Float16* dst = (_Float16*)kvh +
        (((size_t)(b * NH + head) * NSEQ) + a * 64 + nt * 16 + lc) * 16 + sb;
    f16x4 pk, pv;
    pk[0]=(_Float16)acck[nt][0]; pk[1]=(_Float16)acck[nt][1];
    pk[2]=(_Float16)acck[nt][2]; pk[3]=(_Float16)acck[nt][3];
    pv[0]=(_Float16)accv[nt][0]; pv[1]=(_Float16)accv[nt][1];
    pv[2]=(_Float16)accv[nt][2]; pv[3]=(_Float16)accv[nt][3];
    *(f16x4*)dst = pk;
    *(f16x4*)(dst + 8) = pv;
  }

  // agent via mean-first (linearity of pooling): f32 all the way.
  if (t < 64) marr[t] = red[0][t] + red[1][t] + red[2][t] + red[3][t];
  __syncthreads();
  if (t < 64) {
    const float4* wqr = (const float4*)(Wq + (size_t)t * NDIM);
    const float4* mm = (const float4*)marr;
    float s0 = 0.f;
#pragma unroll
    for (int i = 0; i < 16; ++i) {
      float4 wv4 = wqr[i], m4 = mm[i];
      s0 += wv4.x * m4.x + wv4.y * m4.y + wv4.z * m4.z + wv4.w * m4.w;
    }
    agent[(((size_t)b * NH + (t >> 3)) * NAG + a) * 8 + (t & 7)] =
        s0 * (kScale * kLog2e / 64.f);
  }
}

// ---------------------------------------------------------------------------
// Kernel B: stage-0 attention partials. pvs[b,h,a] = [sum_p*v (8) | sum_p | pad3]
// (UNNORMALIZED; kernel C divides). grid (8, 32, 4) token-split, block 256
// (4 waves; wave = 196 tokens). Manual double-buffered register prefetch
// (4 tokens/group, static indices) keeps 8x16B loads in flight.
// ---------------------------------------------------------------------------
__global__ __launch_bounds__(256, 4) void stage0_kernel(
    const us* __restrict__ kvh, const float* __restrict__ agent,
    float* __restrict__ pvs) {
  __shared__ float red[4][NAG][9]; // 7056B
  const int h = blockIdx.x, b = blockIdx.y, z = blockIdx.z;
  const int t = threadIdx.x, lane = t & 63;
  const int w = __builtin_amdgcn_readfirstlane(t >> 6);
  const int a = lane < NAG ? lane : NAG - 1;

  f16x2 ah0, ah1, ah2, ah3;
  float a0,a1,a2,a3,a4,a5,a6,a7;
  {
    const float4* ap = (const float4*)(agent + (((size_t)b * NH + h) * NAG + a) * 8);
    float4 g0 = ap[0], g1 = ap[1];
    a0=g0.x; a1=g0.y; a2=g0.z; a3=g0.w; a4=g1.x; a5=g1.y; a6=g1.z; a7=g1.w;
    ah0 = (f16x2){(_Float16)g0.x, (_Float16)g0.y};
    ah1 = (f16x2){(_Float16)g0.z, (_Float16)g0.w};
    ah2 = (f16x2){(_Float16)g1.x, (_Float16)g1.y};
    ah3 = (f16x2){(_Float16)g1.z, (_Float16)g1.w};
  }
  const us* kb = kvh + (((size_t)b * NH + h) * NSEQ + z * 784 + w * 196) * 16;

  float s = 0.f;
  float o0=0,o1=0,o2=0,o3=0,o4=0,o5=0,o6=0,o7=0;

  uint4 Ak[4], Av[4], Bk[4], Bv[4];

  auto LOADG_A = [&](int g) {
    const us* p = kb + (size_t)g * 64;
#pragma unroll
    for (int i = 0; i < 4; ++i) {
      Ak[i] = *(const uint4*)(p + i * 16);
      Av[i] = *(const uint4*)(p + i * 16 + 8);
    }
  };
  auto LOADG_B = [&](int g) {
    const us* p = kb + (size_t)g * 64;
#pragma unroll
    for (int i = 0; i < 4; ++i) {
      Bk[i] = *(const uint4*)(p + i * 16);
      Bv[i] = *(const uint4*)(p + i * 16 + 8);
    }
  };
  auto COMP = [&](const uint4 (&bk)[4], const uint4 (&bv)[4]) {
#pragma unroll
    for (int i = 0; i < 4; ++i) {
      uint4 ku = bk[i], vu = bv[i];
      float lg;
#if __has_builtin(__builtin_amdgcn_fdot2)
      lg = __builtin_amdgcn_fdot2(ah0, __builtin_bit_cast(f16x2, ku.x), 0.f, false);
      lg = __builtin_amdgcn_fdot2(ah1, __builtin_bit_cast(f16x2, ku.y), lg, false);
      lg = __builtin_amdgcn_fdot2(ah2, __builtin_bit_cast(f16x2, ku.z), lg, false);
      lg = __builtin_amdgcn_fdot2(ah3, __builtin_bit_cast(f16x2, ku.w), lg, false);
#else
      f16x2 k01 = __builtin_bit_cast(f16x2, ku.x), k23 = __builtin_bit_cast(f16x2, ku.y);
      f16x2 k45 = __builtin_bit_cast(f16x2, ku.z), k67 = __builtin_bit_cast(f16x2, ku.w);
      lg = a0*(float)k01[0] + a1*(float)k01[1] + a2*(float)k23[0] + a3*(float)k23[1]
         + a4*(float)k45[0] + a5*(float)k45[1] + a6*(float)k67[0] + a7*(float)k67[1];
#endif
      float p = fexp2(lg);
      s += p;
      f16x2 v01 = __builtin_bit_cast(f16x2, vu.x), v23 = __builtin_bit_cast(f16x2, vu.y);
      f16x2 v45 = __builtin_bit_cast(f16x2, vu.z), v67 = __builtin_bit_cast(f16x2, vu.w);
      o0 += p * (float)v01[0]; o1 += p * (float)v01[1];
      o2 += p * (float)v23[0]; o3 += p * (float)v23[1];
      o4 += p * (float)v45[0]; o5 += p * (float)v45[1];
      o6 += p * (float)v67[0]; o7 += p * (float)v67[1];
    }
  };

  // 49 groups of 4 tokens: software-pipelined, two named buffers (static idx)
  LOADG_A(0);
#pragma unroll 1
  for (int gg = 0; gg < 24; ++gg) {
    LOADG_B(2 * gg + 1);
    COMP(Ak, Av);
    LOADG_A(2 * gg + 2);
    COMP(Bk, Bv);
  }
  COMP(Ak, Av); // g=48

  if (lane < NAG) {
    float* rr = red[w][lane];
    rr[0] = o0; rr[1] = o1; rr[2] = o2; rr[3] = o3;
    rr[4] = o4; rr[5] = o5; rr[6] = o6; rr[7] = o7; rr[8] = s;
  }
  __syncthreads();
  // flush 441 partial entries with 256 threads (strided; fixes r2 bug)
  for (int idx = t; idx < NAG * 9; idx += 256) {
    const int ra = idx / 9, rc = idx % 9;
    float v = red[0][ra][rc] + red[1][ra][rc] + red[2][ra][rc] + red[3][ra][rc];
    atomicAdd(&pvs[(((size_t)b * NH + h) * NAG + ra) * 12 + rc], v);
  }
}

// ---------------------------------------------------------------------------
// Kernel C: stage-1 attention + output linear, fused.
// grid (49, 32), block 512 (8 waves). 3 barriers. agent/pvs streamed
// wave-uniform; per-agent normalization via v_rcp (1 per agent-iter).
// ---------------------------------------------------------------------------
__global__ __launch_bounds__(512, 4) void stage1_out_kernel(
    const float* __restrict__ x1, const __bf16* __restrict__ wq,
    const float* __restrict__ agent, const float* __restrict__ pvs,
    const __bf16* __restrict__ wo, const float* __restrict__ bo,
    float* __restrict__ out) {
  __shared__ __align__(16) __bf16 xa[64][72];
  __shared__ __align__(16) __bf16 qld[64][72];
  __shared__ __align__(16) __bf16 catL[64][72];
  const int tile = blockIdx.x, b = blockIdx.y;
  const int t = threadIdx.x, tokl = t & 63, h = t >> 6;
  const int w = h, lr = (t >> 4) & 3, lc = t & 15;
  const int mtile = w & 3, thalf = w >> 2;

  // prefetch weight A-frags + bias (global; overlap with staging + barriers)
  bf16x8 wqf0 = *(const bf16x8*)(wq + (size_t)(mtile * 16 + lc) * NDIM + lr * 8);
  bf16x8 wqf1 = *(const bf16x8*)(wq + (size_t)(mtile * 16 + lc) * NDIM + 32 + lr * 8);
  bf16x8 wof[4];
#pragma unroll
  for (int ks = 0; ks < 4; ++ks)
    wof[ks] = *(const bf16x8*)(wo + (size_t)(w * 16 + lc) * 128 + ks * 32 + lr * 8);
  f32x4 bv = *(const f32x4*)(bo + w * 16 + lr * 4);

  // stage x1 tile bf16 (thread: token tokl, cols h*8..h*8+7)
  {
    const float4* src = (const float4*)(x1 + ((size_t)b * NSEQ + tile * 64 + tokl) * NDIM + h * 8);
    float4 v0 = src[0], v1 = src[1];
    bf16x8 p;
    p[0]=(__bf16)v0.x; p[1]=(__bf16)v0.y; p[2]=(__bf16)v0.z; p[3]=(__bf16)v0.w;
    p[4]=(__bf16)v1.x; p[5]=(__bf16)v1.y; p[6]=(__bf16)v1.z; p[7]=(__bf16)v1.w;
    *(bf16x8*)&xa[tokl][h * 8] = p;
  }
  __syncthreads();

  // q^T = Wq @ x1^T (wave w: feat tile mtile, token half thalf) -> qld bf16
  {
    f32x4 aq[2];
    aq[0] = (f32x4){0.f,0.f,0.f,0.f}; aq[1] = (f32x4){0.f,0.f,0.f,0.f};
#pragma unroll
    for (int nt = 0; nt < 2; ++nt) {
      bf16x8 bx0 = *(const bf16x8*)&xa[thalf * 32 + nt * 16 + lc][lr * 8];
      bf16x8 bx1 = *(const bf16x8*)&xa[thalf * 32 + nt * 16 + lc][32 + lr * 8];
      aq[nt] = __builtin_amdgcn_mfma_f32_16x16x32_bf16(wqf0, bx0, aq[nt], 0, 0, 0);
      aq[nt] = __builtin_amdgcn_mfma_f32_16x16x32_bf16(wqf1, bx1, aq[nt], 0, 0, 0);
    }
#pragma unroll
    for (int nt = 0; nt < 2; ++nt) {
      bf16x4 pk;
      pk[0]=(__bf16)aq[nt][0]; pk[1]=(__bf16)aq[nt][1];
      pk[2]=(__bf16)aq[nt][2]; pk[3]=(__bf16)aq[nt][3];
      *(bf16x4*)&qld[thalf * 32 + nt * 16 + lc][mtile * 16 + lr * 4] = pk;
    }
  }
  __syncthreads();

  // stage-1 attention: thread = (tokl, h); agent+pvs streamed wave-uniform
  {
    uint4 qv = *(const uint4*)&qld[tokl][h * 8];
    f32x2 q01 = up2(qv.x), q23 = up2(qv.y), q45 = up2(qv.z), q67 = up2(qv.w);
    const int hh = __builtin_amdgcn_readfirstlane(h);
    const float* agb = agent + (((size_t)b * NH + hh) * NAG) * 8;
    const float* pvb = pvs + (((size_t)b * NH + hh) * NAG) * 12;
    float s = 0.f;
    f32x2 o01 = {0.f,0.f}, o23 = {0.f,0.f}, o45 = {0.f,0.f}, o67 = {0.f,0.f};
#pragma unroll 7
    for (int a2 = 0; a2 < NAG; ++a2) {
      const f32x2* qa = (const f32x2*)(agb + (size_t)a2 * 8);
      f32x2 d = q01 * qa[0];
      d += q23 * qa[1];
      d += q45 * qa[2];
      d += q67 * qa[3];
      float p = fexp2(d[0] + d[1]);
      s += p;
      const f32x2* r = (const f32x2*)(pvb + (size_t)a2 * 12);
      float sden = pvb[(size_t)a2 * 12 + 8];
#if __has_builtin(__builtin_amdgcn_rcpf)
      float pi = p * __builtin_amdgcn_rcpf(sden);
#else
      float pi = p / sden;
#endif
      f32x2 pp = {pi, pi};
      o01 += pp * r[0]; o23 += pp * r[1]; o45 += pp * r[2]; o67 += pp * r[3];
    }
#if __has_builtin(__builtin_amdgcn_rcpf)
    float inv = __builtin_amdgcn_rcpf(s);
#else
    float inv = 1.f / s;
#endif
    bf16x8 pc;
    pc[0]=(__bf16)(o01[0]*inv); pc[1]=(__bf16)(o01[1]*inv);
    pc[2]=(__bf16)(o23[0]*inv); pc[3]=(__bf16)(o23[1]*inv);
    pc[4]=(__bf16)(o45[0]*inv); pc[5]=(__bf16)(o45[1]*inv);
    pc[6]=(__bf16)(o67[0]*inv); pc[7]=(__bf16)(o67[1]*inv);
    *(bf16x8*)&catL[tokl][h * 8] = pc;
  }
  __syncthreads();

  // out^T = Wo @ [catL|xa]^T; direct stores (lane: 4 consecutive feats of 1 tok)
  {
    f32x4 acc[4];
#pragma unroll
    for (int i = 0; i < 4; ++i) acc[i] = (f32x4){0.f,0.f,0.f,0.f};
#pragma unroll
    for (int ks = 0; ks < 4; ++ks) {
#pragma unroll
      for (int nt = 0; nt < 4; ++nt) {
        bf16x8 bx = (ks < 2) ? *(const bf16x8*)&catL[nt * 16 + lc][ks * 32 + lr * 8]
                             : *(const bf16x8*)&xa[nt * 16 + lc][(ks - 2) * 32 + lr * 8];
        acc[nt] = __builtin_amdgcn_mfma_f32_16x16x32_bf16(wof[ks], bx, acc[nt], 0, 0, 0);
      }
    }
#pragma unroll
    for (int nt = 0; nt < 4; ++nt) {
      f32x4 v = acc[nt] + bv;
      float* dst = out + ((size_t)b * NSEQ + tile * 64 + nt * 16 + lc) * 128 + w * 16 + lr * 4;
      *(f32x4*)dst = v;
    }
  }
}

extern "C" void kernel_launch(void* const* d_in, const int* in_sizes, int n_in,
                              void* d_out, int out_size, void* d_ws, size_t ws_size,
                              hipStream_t stream) {
  (void)in_sizes; (void)n_in; (void)out_size; (void)ws_size;
  const float* x1 = (const float*)d_in[0];
  const float* x2 = (const float*)d_in[1];
  const float* Wq = (const float*)d_in[2];
  const float* Wk = (const float*)d_in[3];
  const float* Wv = (const float*)d_in[4];
  const float* Wo = (const float*)d_in[5];
  const float* bo = (const float*)d_in[6];
  float* out = (float*)d_out;

  us* kvh = (us*)d_ws;                                        // 32*8*3136*16 f16 = 25.7MB
  float* agent = (float*)(kvh + (size_t)NB * NH * NSEQ * 16); // 100352 f32
  float* pvs = agent + (size_t)NB * NH * NAG * 8;             // 150528 f32 (rows of 12)
  __bf16* wq_bf = (__bf16*)(pvs + (size_t)NB * NH * NAG * 12);
  __bf16* wk_bf = wq_bf + 4096;
  __bf16* wv_bf = wk_bf + 4096;
  __bf16* wo_bf = wv_bf + 4096;
  // total ws ~= 27 MB

  prep_kernel<<<dim3(64), 256, 0, stream>>>(Wq, Wk, Wv, Wo, wq_bf, wk_bf, wv_bf, wo_bf, pvs);
  qkv_agent_kernel<<<dim3(NAG, NB), 256, 0, stream>>>(x1, x2, Wq, wk_bf, wv_bf, kvh, agent);
  stage0_kernel<<<dim3(NH, NB, 4), 256, 0, stream>>>(kvh, agent, pvs);
  stage1_out_kernel<<<dim3(NAG, NB), 512, 0, stream>>>(x1, wq_bf, agent, pvs, wo_bf, bo, out);
}

// Round 4
// 101.729 us; speedup vs baseline: 1.0604x; 1.0604x over previous
//
#include <hip/hip_runtime.h>
#include <hip/hip_bf16.h>

#define NB 32
#define NSEQ 3136
#define NDIM 64
#define NH 8
#define NAG 49

static constexpr float kScale = 0.35355339059327378f; // 8^-0.5
static constexpr float kLog2e = 1.4426950408889634f;

typedef unsigned short us;
typedef __attribute__((ext_vector_type(8))) __bf16 bf16x8;
typedef __attribute__((ext_vector_type(4))) __bf16 bf16x4;
typedef __attribute__((ext_vector_type(2))) _Float16 f16x2;
typedef __attribute__((ext_vector_type(4))) _Float16 f16x4;
typedef __attribute__((ext_vector_type(4))) float f32x4;
typedef __attribute__((ext_vector_type(2))) float f32x2;

__device__ __forceinline__ f32x2 up2(unsigned int u) { // {lo,hi} bf16 pair -> f32x2
  return (f32x2){__uint_as_float(u << 16), __uint_as_float(u & 0xffff0000u)};
}

__device__ __forceinline__ float fexp2(float x) {
#if __has_builtin(__builtin_amdgcn_exp2f)
  return __builtin_amdgcn_exp2f(x);
#else
  return exp2f(x);
#endif
}

__device__ __forceinline__ float frcp(float x) {
#if __has_builtin(__builtin_amdgcn_rcpf)
  return __builtin_amdgcn_rcpf(x);
#else
  return 1.f / x;
#endif
}

// ---------------------------------------------------------------------------
// Kernel P: convert Wq,Wk,Wv (64x64) and Wo (128x128) to bf16; zero pvs.
// ---------------------------------------------------------------------------
__global__ __launch_bounds__(256) void prep_kernel(
    const float* __restrict__ Wq, const float* __restrict__ Wk,
    const float* __restrict__ Wv, const float* __restrict__ Wo,
    __bf16* __restrict__ wq, __bf16* __restrict__ wk, __bf16* __restrict__ wv,
    __bf16* __restrict__ wo, float* __restrict__ pvs) {
  int i = blockIdx.x * 256 + threadIdx.x; // 64 blocks -> 16384
  wo[i] = (__bf16)Wo[i];
  if (i < 4096) { wq[i] = (__bf16)Wq[i]; wk[i] = (__bf16)Wk[i]; wv[i] = (__bf16)Wv[i]; }
  for (int j = i; j < NB * NH * NAG * 12; j += 16384) pvs[j] = 0.f;
}

// ---------------------------------------------------------------------------
// Kernel A: kv^T GEMM via swapped MFMA operands (C = W @ x2^T) so each lane
// holds 4 consecutive FEATURES of one token -> direct f16 global stores, no
// LDS transpose. agent = log2e * kScale * (colsum(x1)/64) @ Wq^T in f32.
// kvh[b,h,j][0..7]=k f16, [8..15]=v f16. grid (49,32), block 256 (4 waves).
// ---------------------------------------------------------------------------
__global__ __launch_bounds__(256, 4) void qkv_agent_kernel(
    const float* __restrict__ x1, const float* __restrict__ x2,
    const float* __restrict__ Wq, const __bf16* __restrict__ wk,
    const __bf16* __restrict__ wv, us* __restrict__ kvh,
    float* __restrict__ agent) {
  __shared__ __align__(16) __bf16 xb[64][72];
  __shared__ __align__(16) float red[4][64];
  __shared__ __align__(16) float marr[64];
  const int a = blockIdx.x, b = blockIdx.y, t = threadIdx.x;
  const int i64 = t & 63, cb = t >> 6;
  const int w = cb, lr = (t >> 4) & 3, lc = t & 15;

  // prefetch A-frags (W rows; independent of LDS, overlaps staging)
  bf16x8 ak0 = *(const bf16x8*)(wk + (size_t)(w * 16 + lc) * NDIM + lr * 8);
  bf16x8 ak1 = *(const bf16x8*)(wk + (size_t)(w * 16 + lc) * NDIM + 32 + lr * 8);
  bf16x8 av0 = *(const bf16x8*)(wv + (size_t)(w * 16 + lc) * NDIM + lr * 8);
  bf16x8 av1 = *(const bf16x8*)(wv + (size_t)(w * 16 + lc) * NDIM + 32 + lr * 8);

  // stage x2 tile as bf16 (thread: one row, 16 cols)
  {
    const float4* s2 = (const float4*)(x2 + ((size_t)(b * NSEQ) + a * 64 + i64) * NDIM + cb * 16);
    float4 v0 = s2[0], v1 = s2[1], v2 = s2[2], v3 = s2[3];
    bf16x8 p0, p1;
    p0[0]=(__bf16)v0.x; p0[1]=(__bf16)v0.y; p0[2]=(__bf16)v0.z; p0[3]=(__bf16)v0.w;
    p0[4]=(__bf16)v1.x; p0[5]=(__bf16)v1.y; p0[6]=(__bf16)v1.z; p0[7]=(__bf16)v1.w;
    p1[0]=(__bf16)v2.x; p1[1]=(__bf16)v2.y; p1[2]=(__bf16)v2.z; p1[3]=(__bf16)v2.w;
    p1[4]=(__bf16)v3.x; p1[5]=(__bf16)v3.y; p1[6]=(__bf16)v3.z; p1[7]=(__bf16)v3.w;
    *(bf16x8*)&xb[i64][cb * 16] = p0; *(bf16x8*)&xb[i64][cb * 16 + 8] = p1;
  }
  // x1 column partial sums (wave reads are fully coalesced: 64 lanes = 64 cols)
  {
    const float* xc = x1 + ((size_t)(b * NSEQ) + a * 64 + cb * 16) * NDIM + i64;
    float cs = 0.f;
#pragma unroll
    for (int i = 0; i < 16; ++i) cs += xc[i * NDIM];
    red[cb][i64] = cs;
  }
  __syncthreads();

  // kv^T GEMM: wave w covers k-feats [w*16,w*16+16) and v-feats likewise.
  f32x4 acck[4], accv[4];
#pragma unroll
  for (int i = 0; i < 4; ++i) {
    acck[i] = (f32x4){0.f, 0.f, 0.f, 0.f};
    accv[i] = (f32x4){0.f, 0.f, 0.f, 0.f};
  }
#pragma unroll
  for (int nt = 0; nt < 4; ++nt) {
    bf16x8 x0 = *(const bf16x8*)&xb[nt * 16 + lc][lr * 8];
    bf16x8 x1f = *(const bf16x8*)&xb[nt * 16 + lc][32 + lr * 8];
    acck[nt] = __builtin_amdgcn_mfma_f32_16x16x32_bf16(ak0, x0, acck[nt], 0, 0, 0);
    acck[nt] = __builtin_amdgcn_mfma_f32_16x16x32_bf16(ak1, x1f, acck[nt], 0, 0, 0);
    accv[nt] = __builtin_amdgcn_mfma_f32_16x16x32_bf16(av0, x0, accv[nt], 0, 0, 0);
    accv[nt] = __builtin_amdgcn_mfma_f32_16x16x32_bf16(av1, x1f, accv[nt], 0, 0, 0);
  }
  // C layout: row = feat = lr*4+j (within wave's 16), col = tok = nt*16+lc.
  // feat f = w*16+lr*4+j -> head = f>>3 = 2w + (lr>>1), slot = (lr&1)*4 + j.
  const int head = 2 * w + (lr >> 1), sb = (lr & 1) * 4;
#pragma unroll
  for (int nt = 0; nt < 4; ++nt) {
    _Float16* dst = (_Float16*)kvh +
        (((size_t)(b * NH + head) * NSEQ) + a * 64 + nt * 16 + lc) * 16 + sb;
    f16x4 pk, pv;
    pk[0]=(_Float16)acck[nt][0]; pk[1]=(_Float16)acck[nt][1];
    pk[2]=(_Float16)acck[nt][2]; pk[3]=(_Float16)acck[nt][3];
    pv[0]=(_Float16)accv[nt][0]; pv[1]=(_Float16)accv[nt][1];
    pv[2]=(_Float16)accv[nt][2]; pv[3]=(_Float16)accv[nt][3];
    *(f16x4*)dst = pk;
    *(f16x4*)(dst + 8) = pv;
  }

  // agent via mean-first (linearity of pooling): f32 all the way.
  if (t < 64) marr[t] = red[0][t] + red[1][t] + red[2][t] + red[3][t];
  __syncthreads();
  if (t < 64) {
    const float4* wqr = (const float4*)(Wq + (size_t)t * NDIM);
    const float4* mm = (const float4*)marr;
    float s0 = 0.f;
#pragma unroll
    for (int i = 0; i < 16; ++i) {
      float4 wv4 = wqr[i], m4 = mm[i];
      s0 += wv4.x * m4.x + wv4.y * m4.y + wv4.z * m4.z + wv4.w * m4.w;
    }
    agent[(((size_t)b * NH + (t >> 3)) * NAG + a) * 8 + (t & 7)] =
        s0 * (kScale * kLog2e / 64.f);
  }
}

// ---------------------------------------------------------------------------
// Kernel B: stage-0 attention partials. pvs[b,h,a] = [sum_p*v (8) | sum_p | pad3]
// (UNNORMALIZED; kernel C divides). grid (8, 32, 8) token-split, block 256
// (4 waves; wave = 98 tokens). 8 blocks/CU -> 32 waves/CU (100% occupancy);
// 2-token register double-buffer fits the 64-VGPR cap of (256,8).
// ---------------------------------------------------------------------------
__global__ __launch_bounds__(256, 8) void stage0_kernel(
    const us* __restrict__ kvh, const float* __restrict__ agent,
    float* __restrict__ pvs) {
  __shared__ float red[4][NAG][9]; // 7056B
  const int h = blockIdx.x, b = blockIdx.y, z = blockIdx.z;
  const int t = threadIdx.x, lane = t & 63;
  const int w = __builtin_amdgcn_readfirstlane(t >> 6);
  const int a = lane < NAG ? lane : NAG - 1;

  f16x2 ah0, ah1, ah2, ah3;
  float a0,a1,a2,a3,a4,a5,a6,a7;
  {
    const float4* ap = (const float4*)(agent + (((size_t)b * NH + h) * NAG + a) * 8);
    float4 g0 = ap[0], g1 = ap[1];
    a0=g0.x; a1=g0.y; a2=g0.z; a3=g0.w; a4=g1.x; a5=g1.y; a6=g1.z; a7=g1.w;
    ah0 = (f16x2){(_Float16)g0.x, (_Float16)g0.y};
    ah1 = (f16x2){(_Float16)g0.z, (_Float16)g0.w};
    ah2 = (f16x2){(_Float16)g1.x, (_Float16)g1.y};
    ah3 = (f16x2){(_Float16)g1.z, (_Float16)g1.w};
  }
  const us* kb = kvh + (((size_t)b * NH + h) * NSEQ + z * 392 + w * 98) * 16;

  float s = 0.f;
  float o0=0,o1=0,o2=0,o3=0,o4=0,o5=0,o6=0,o7=0;

  uint4 Ak[2], Av[2], Bk[2], Bv[2];

  auto LOADG_A = [&](int g) {
    const us* p = kb + (size_t)g * 32;
#pragma unroll
    for (int i = 0; i < 2; ++i) {
      Ak[i] = *(const uint4*)(p + i * 16);
      Av[i] = *(const uint4*)(p + i * 16 + 8);
    }
  };
  auto LOADG_B = [&](int g) {
    const us* p = kb + (size_t)g * 32;
#pragma unroll
    for (int i = 0; i < 2; ++i) {
      Bk[i] = *(const uint4*)(p + i * 16);
      Bv[i] = *(const uint4*)(p + i * 16 + 8);
    }
  };
  auto COMP = [&](const uint4 (&bk)[2], const uint4 (&bv)[2]) {
#pragma unroll
    for (int i = 0; i < 2; ++i) {
      uint4 ku = bk[i], vu = bv[i];
      float lg;
#if __has_builtin(__builtin_amdgcn_fdot2)
      lg = __builtin_amdgcn_fdot2(ah0, __builtin_bit_cast(f16x2, ku.x), 0.f, false);
      lg = __builtin_amdgcn_fdot2(ah1, __builtin_bit_cast(f16x2, ku.y), lg, false);
      lg = __builtin_amdgcn_fdot2(ah2, __builtin_bit_cast(f16x2, ku.z), lg, false);
      lg = __builtin_amdgcn_fdot2(ah3, __builtin_bit_cast(f16x2, ku.w), lg, false);
#else
      f16x2 k01 = __builtin_bit_cast(f16x2, ku.x), k23 = __builtin_bit_cast(f16x2, ku.y);
      f16x2 k45 = __builtin_bit_cast(f16x2, ku.z), k67 = __builtin_bit_cast(f16x2, ku.w);
      lg = a0*(float)k01[0] + a1*(float)k01[1] + a2*(float)k23[0] + a3*(float)k23[1]
         + a4*(float)k45[0] + a5*(float)k45[1] + a6*(float)k67[0] + a7*(float)k67[1];
#endif
      float p = fexp2(lg);
      s += p;
      f16x2 v01 = __builtin_bit_cast(f16x2, vu.x), v23 = __builtin_bit_cast(f16x2, vu.y);
      f16x2 v45 = __builtin_bit_cast(f16x2, vu.z), v67 = __builtin_bit_cast(f16x2, vu.w);
      o0 += p * (float)v01[0]; o1 += p * (float)v01[1];
      o2 += p * (float)v23[0]; o3 += p * (float)v23[1];
      o4 += p * (float)v45[0]; o5 += p * (float)v45[1];
      o6 += p * (float)v67[0]; o7 += p * (float)v67[1];
    }
  };

  // 49 groups of 2 tokens: software-pipelined, two named buffers (static idx)
  LOADG_A(0);
#pragma unroll 1
  for (int gg = 0; gg < 24; ++gg) {
    LOADG_B(2 * gg + 1);
    COMP(Ak, Av);
    LOADG_A(2 * gg + 2);
    COMP(Bk, Bv);
  }
  COMP(Ak, Av); // g=48

  if (lane < NAG) {
    float* rr = red[w][lane];
    rr[0] = o0; rr[1] = o1; rr[2] = o2; rr[3] = o3;
    rr[4] = o4; rr[5] = o5; rr[6] = o6; rr[7] = o7; rr[8] = s;
  }
  __syncthreads();
  // flush 441 partial entries with 256 threads (strided)
  for (int idx = t; idx < NAG * 9; idx += 256) {
    const int ra = idx / 9, rc = idx % 9;
    float v = red[0][ra][rc] + red[1][ra][rc] + red[2][ra][rc] + red[3][ra][rc];
    atomicAdd(&pvs[(((size_t)b * NH + h) * NAG + ra) * 12 + rc], v);
  }
}

// ---------------------------------------------------------------------------
// Kernel C: stage-1 attention + output linear, fused.
// grid (49, 32), block 512 (8 waves), 3 blocks/CU. ao tables staged+normalized
// into LDS once per block (broadcast reads in the 49-loop); qld/catL merged
// (owner-thread read-then-write) to fit 3-block LDS budget.
// ---------------------------------------------------------------------------
__global__ __launch_bounds__(512, 6) void stage1_out_kernel(
    const float* __restrict__ x1, const __bf16* __restrict__ wq,
    const float* __restrict__ agent, const float* __restrict__ pvs,
    const __bf16* __restrict__ wo, const float* __restrict__ bo,
    float* __restrict__ out) {
  __shared__ __align__(16) __bf16 xa[64][72];     // 9216
  __shared__ __align__(16) __bf16 qcat[64][72];   // 9216 (q, then catL in-place)
  __shared__ __align__(16) float aot[392 * 20];   // 31360 ([agent8|pv/s 8|pad4], stride 20)
  const int tile = blockIdx.x, b = blockIdx.y;
  const int t = threadIdx.x, tokl = t & 63, h = t >> 6;
  const int w = h, lr = (t >> 4) & 3, lc = t & 15;
  const int mtile = w & 3, thalf = w >> 2;

  // prefetch weight A-frags + bias (global; overlap with staging + barriers)
  bf16x8 wqf0 = *(const bf16x8*)(wq + (size_t)(mtile * 16 + lc) * NDIM + lr * 8);
  bf16x8 wqf1 = *(const bf16x8*)(wq + (size_t)(mtile * 16 + lc) * NDIM + 32 + lr * 8);
  bf16x8 wof[4];
#pragma unroll
  for (int ks = 0; ks < 4; ++ks)
    wof[ks] = *(const bf16x8*)(wo + (size_t)(w * 16 + lc) * 128 + ks * 32 + lr * 8);
  f32x4 bv = *(const f32x4*)(bo + w * 16 + lr * 4);

  // issue ao-table global loads early (written to LDS after q-GEMM)
  float4 ag0, ag1, pv0, pv1, pv2;
  if (t < NH * NAG) {
    const int hi = t / NAG, ai = t - hi * NAG;
    const float* ap = agent + (((size_t)b * NH + hi) * NAG + ai) * 8;
    const float* pp = pvs + (((size_t)b * NH + hi) * NAG + ai) * 12;
    ag0 = *(const float4*)ap; ag1 = *(const float4*)(ap + 4);
    pv0 = *(const float4*)pp; pv1 = *(const float4*)(pp + 4);
    pv2 = *(const float4*)(pp + 8); // .x = sum_p
  }

  // stage x1 tile bf16 (thread: token tokl, cols h*8..h*8+7)
  {
    const float4* src = (const float4*)(x1 + ((size_t)b * NSEQ + tile * 64 + tokl) * NDIM + h * 8);
    float4 v0 = src[0], v1 = src[1];
    bf16x8 p;
    p[0]=(__bf16)v0.x; p[1]=(__bf16)v0.y; p[2]=(__bf16)v0.z; p[3]=(__bf16)v0.w;
    p[4]=(__bf16)v1.x; p[5]=(__bf16)v1.y; p[6]=(__bf16)v1.z; p[7]=(__bf16)v1.w;
    *(bf16x8*)&xa[tokl][h * 8] = p;
  }
  __syncthreads();

  // q^T = Wq @ x1^T (wave w: feat tile mtile, token half thalf) -> qcat bf16
  {
    f32x4 aq[2];
    aq[0] = (f32x4){0.f,0.f,0.f,0.f}; aq[1] = (f32x4){0.f,0.f,0.f,0.f};
#pragma unroll
    for (int nt = 0; nt < 2; ++nt) {
      bf16x8 bx0 = *(const bf16x8*)&xa[thalf * 32 + nt * 16 + lc][lr * 8];
      bf16x8 bx1 = *(const bf16x8*)&xa[thalf * 32 + nt * 16 + lc][32 + lr * 8];
      aq[nt] = __builtin_amdgcn_mfma_f32_16x16x32_bf16(wqf0, bx0, aq[nt], 0, 0, 0);
      aq[nt] = __builtin_amdgcn_mfma_f32_16x16x32_bf16(wqf1, bx1, aq[nt], 0, 0, 0);
    }
#pragma unroll
    for (int nt = 0; nt < 2; ++nt) {
      bf16x4 pk;
      pk[0]=(__bf16)aq[nt][0]; pk[1]=(__bf16)aq[nt][1];
      pk[2]=(__bf16)aq[nt][2]; pk[3]=(__bf16)aq[nt][3];
      *(bf16x4*)&qcat[thalf * 32 + nt * 16 + lc][mtile * 16 + lr * 4] = pk;
    }
  }
  // ao table -> LDS, normalized during staging (1 rcp per row, off hot loop)
  if (t < NH * NAG) {
    float inv = frcp(pv2.x);
    float* dst = aot + t * 20;
    *(float4*)dst = ag0;
    *(float4*)(dst + 4) = ag1;
    *(float4*)(dst + 8)  = (float4){pv0.x*inv, pv0.y*inv, pv0.z*inv, pv0.w*inv};
    *(float4*)(dst + 12) = (float4){pv1.x*inv, pv1.y*inv, pv1.z*inv, pv1.w*inv};
  }
  __syncthreads();

  // stage-1 attention: thread = (tokl, h); table reads are LDS broadcasts
  {
    uint4 qv = *(const uint4*)&qcat[tokl][h * 8];
    f32x2 q01 = up2(qv.x), q23 = up2(qv.y), q45 = up2(qv.z), q67 = up2(qv.w);
    const float* hrow = aot + h * (NAG * 20);
    float s = 0.f;
    f32x2 o01 = {0.f,0.f}, o23 = {0.f,0.f}, o45 = {0.f,0.f}, o67 = {0.f,0.f};
#pragma unroll 7
    for (int a2 = 0; a2 < NAG; ++a2) {
      const float* r = hrow + a2 * 20;
      f32x4 A0 = *(const f32x4*)r,        A1 = *(const f32x4*)(r + 4);
      f32x4 P0 = *(const f32x4*)(r + 8),  P1 = *(const f32x4*)(r + 12);
      f32x2 d = q01 * (f32x2){A0[0], A0[1]};
      d += q23 * (f32x2){A0[2], A0[3]};
      d += q45 * (f32x2){A1[0], A1[1]};
      d += q67 * (f32x2){A1[2], A1[3]};
      float p = fexp2(d[0] + d[1]);
      s += p;
      f32x2 pp = {p, p};
      o01 += pp * (f32x2){P0[0], P0[1]}; o23 += pp * (f32x2){P0[2], P0[3]};
      o45 += pp * (f32x2){P1[0], P1[1]}; o67 += pp * (f32x2){P1[2], P1[3]};
    }
    float inv = frcp(s);
    bf16x8 pc;
    pc[0]=(__bf16)(o01[0]*inv); pc[1]=(__bf16)(o01[1]*inv);
    pc[2]=(__bf16)(o23[0]*inv); pc[3]=(__bf16)(o23[1]*inv);
    pc[4]=(__bf16)(o45[0]*inv); pc[5]=(__bf16)(o45[1]*inv);
    pc[6]=(__bf16)(o67[0]*inv); pc[7]=(__bf16)(o67[1]*inv);
    *(bf16x8*)&qcat[tokl][h * 8] = pc; // owner-thread slot: read q, write catL
  }
  __syncthreads();

  // out^T = Wo @ [catL|xa]^T; direct stores (lane: 4 consecutive feats of 1 tok)
  {
    f32x4 acc[4];
#pragma unroll
    for (int i = 0; i < 4; ++i) acc[i] = (f32x4){0.f,0.f,0.f,0.f};
#pragma unroll
    for (int ks = 0; ks < 4; ++ks) {
#pragma unroll
      for (int nt = 0; nt < 4; ++nt) {
        bf16x8 bx = (ks < 2) ? *(const bf16x8*)&qcat[nt * 16 + lc][ks * 32 + lr * 8]
                             : *(const bf16x8*)&xa[nt * 16 + lc][(ks - 2) * 32 + lr * 8];
        acc[nt] = __builtin_amdgcn_mfma_f32_16x16x32_bf16(wof[ks], bx, acc[nt], 0, 0, 0);
      }
    }
#pragma unroll
    for (int nt = 0; nt < 4; ++nt) {
      f32x4 v = acc[nt] + bv;
      float* dst = out + ((size_t)b * NSEQ + tile * 64 + nt * 16 + lc) * 128 + w * 16 + lr * 4;
      *(f32x4*)dst = v;
    }
  }
}

extern "C" void kernel_launch(void* const* d_in, const int* in_sizes, int n_in,
                              void* d_out, int out_size, void* d_ws, size_t ws_size,
                              hipStream_t stream) {
  (void)in_sizes; (void)n_in; (void)out_size; (void)ws_size;
  const float* x1 = (const float*)d_in[0];
  const float* x2 = (const float*)d_in[1];
  const float* Wq = (const float*)d_in[2];
  const float* Wk = (const float*)d_in[3];
  const float* Wv = (const float*)d_in[4];
  const float* Wo = (const float*)d_in[5];
  const float* bo = (const float*)d_in[6];
  float* out = (float*)d_out;

  us* kvh = (us*)d_ws;                                        // 32*8*3136*16 f16 = 25.7MB
  float* agent = (float*)(kvh + (size_t)NB * NH * NSEQ * 16); // 100352 f32
  float* pvs = agent + (size_t)NB * NH * NAG * 8;             // 150528 f32 (rows of 12)
  __bf16* wq_bf = (__bf16*)(pvs + (size_t)NB * NH * NAG * 12);
  __bf16* wk_bf = wq_bf + 4096;
  __bf16* wv_bf = wk_bf + 4096;
  __bf16* wo_bf = wv_bf + 4096;
  // total ws ~= 27 MB

  prep_kernel<<<dim3(64), 256, 0, stream>>>(Wq, Wk, Wv, Wo, wq_bf, wk_bf, wv_bf, wo_bf, pvs);
  qkv_agent_kernel<<<dim3(NAG, NB), 256, 0, stream>>>(x1, x2, Wq, wk_bf, wv_bf, kvh, agent);
  stage0_kernel<<<dim3(NH, NB, 8), 256, 0, stream>>>(kvh, agent, pvs);
  stage1_out_kernel<<<dim3(NAG, NB), 512, 0, stream>>>(x1, wq_bf, agent, pvs, wo_bf, bo, out);
}

// Round 5
// 86.255 us; speedup vs baseline: 1.2506x; 1.1794x over previous
//
#include <hip/hip_runtime.h>
#include <hip/hip_bf16.h>

#define NB 32
#define NSEQ 3136
#define NDIM 64
#define NH 8
#define NAG 49
#define SPLIT 4

static constexpr float kScale = 0.35355339059327378f; // 8^-0.5
static constexpr float kLog2e = 1.4426950408889634f;

typedef unsigned short us;
typedef __attribute__((ext_vector_type(8))) __bf16 bf16x8;
typedef __attribute__((ext_vector_type(4))) __bf16 bf16x4;
typedef __attribute__((ext_vector_type(2))) _Float16 f16x2;
typedef __attribute__((ext_vector_type(4))) _Float16 f16x4;
typedef __attribute__((ext_vector_type(8))) _Float16 f16x8;
typedef __attribute__((ext_vector_type(4))) float f32x4;
typedef __attribute__((ext_vector_type(2))) float f32x2;

__device__ __forceinline__ f32x2 up2(unsigned int u) { // {lo,hi} bf16 pair -> f32x2
  return (f32x2){__uint_as_float(u << 16), __uint_as_float(u & 0xffff0000u)};
}

__device__ __forceinline__ float fexp2(float x) {
#if __has_builtin(__builtin_amdgcn_exp2f)
  return __builtin_amdgcn_exp2f(x);
#else
  return exp2f(x);
#endif
}

__device__ __forceinline__ float frcp(float x) {
#if __has_builtin(__builtin_amdgcn_rcpf)
  return __builtin_amdgcn_rcpf(x);
#else
  return 1.f / x;
#endif
}

__device__ __forceinline__ unsigned pk2(float a, float b) { // pack 2 f32 -> f16x2
#if __has_builtin(__builtin_amdgcn_cvt_pkrtz)
  return __builtin_bit_cast(unsigned, __builtin_amdgcn_cvt_pkrtz(a, b));
#else
  f16x2 v = {(_Float16)a, (_Float16)b};
  return __builtin_bit_cast(unsigned, v);
#endif
}

// ---------------------------------------------------------------------------
// Kernel P: weights -> bf16; zero kvhk tail pad; vt "ones" row (feat 8) per bh.
// ---------------------------------------------------------------------------
__global__ __launch_bounds__(256) void prep_kernel(
    const float* __restrict__ Wq, const float* __restrict__ Wk,
    const float* __restrict__ Wv, const float* __restrict__ Wo,
    __bf16* __restrict__ wq, __bf16* __restrict__ wk, __bf16* __restrict__ wv,
    __bf16* __restrict__ wo, us* __restrict__ kvhk, us* __restrict__ vt) {
  int i = blockIdx.x * 256 + threadIdx.x; // 64 blocks -> 16384
  wo[i] = (__bf16)Wo[i];
  if (i < 4096) { wq[i] = (__bf16)Wq[i]; wk[i] = (__bf16)Wk[i]; wv[i] = (__bf16)Wv[i]; }
  if (i < 32) kvhk[(size_t)NB * NH * NSEQ * 8 + i] = 0;
  const us one = 0x3C00; // f16 1.0
  for (size_t j = i; j < (size_t)NB * NH * NSEQ; j += 16384) {
    size_t bh = j / NSEQ, tok = j - bh * NSEQ;
    vt[(bh * 9 + 8) * NSEQ + tok] = one;
  }
}

// ---------------------------------------------------------------------------
// Kernel A: kv^T GEMM (swapped MFMA operands). Outputs:
//   kvhk[b,h][tok][8]   k as f16 (row-contig, +32 f16 zero pad at very end)
//   vt  [b,h][9][3136]  V^T as f16 (feature-major; row 8 = ones from prep)
//   agent (f32) + agf16 (f16) = log2e*kScale*(colsum(x1)/64) @ Wq^T
// grid (49,32), block 256 (4 waves).
// ---------------------------------------------------------------------------
__global__ __launch_bounds__(256, 4) void qkv_agent_kernel(
    const float* __restrict__ x1, const float* __restrict__ x2,
    const float* __restrict__ Wq, const __bf16* __restrict__ wk,
    const __bf16* __restrict__ wv, us* __restrict__ kvhk, us* __restrict__ vt,
    float* __restrict__ agent, us* __restrict__ agf16) {
  __shared__ __align__(16) __bf16 xb[64][72];
  __shared__ __align__(16) float red[4][64];
  __shared__ __align__(16) float marr[64];
  const int a = blockIdx.x, b = blockIdx.y, t = threadIdx.x;
  const int i64 = t & 63, cb = t >> 6;
  const int w = cb, lr = (t >> 4) & 3, lc = t & 15;

  // prefetch A-frags (W rows; independent of LDS, overlaps staging)
  bf16x8 ak0 = *(const bf16x8*)(wk + (size_t)(w * 16 + lc) * NDIM + lr * 8);
  bf16x8 ak1 = *(const bf16x8*)(wk + (size_t)(w * 16 + lc) * NDIM + 32 + lr * 8);
  bf16x8 av0 = *(const bf16x8*)(wv + (size_t)(w * 16 + lc) * NDIM + lr * 8);
  bf16x8 av1 = *(const bf16x8*)(wv + (size_t)(w * 16 + lc) * NDIM + 32 + lr * 8);

  // stage x2 tile as bf16 (thread: one row, 16 cols)
  {
    const float4* s2 = (const float4*)(x2 + ((size_t)(b * NSEQ) + a * 64 + i64) * NDIM + cb * 16);
    float4 v0 = s2[0], v1 = s2[1], v2 = s2[2], v3 = s2[3];
    bf16x8 p0, p1;
    p0[0]=(__bf16)v0.x; p0[1]=(__bf16)v0.y; p0[2]=(__bf16)v0.z; p0[3]=(__bf16)v0.w;
    p0[4]=(__bf16)v1.x; p0[5]=(__bf16)v1.y; p0[6]=(__bf16)v1.z; p0[7]=(__bf16)v1.w;
    p1[0]=(__bf16)v2.x; p1[1]=(__bf16)v2.y; p1[2]=(__bf16)v2.z; p1[3]=(__bf16)v2.w;
    p1[4]=(__bf16)v3.x; p1[5]=(__bf16)v3.y; p1[6]=(__bf16)v3.z; p1[7]=(__bf16)v3.w;
    *(bf16x8*)&xb[i64][cb * 16] = p0; *(bf16x8*)&xb[i64][cb * 16 + 8] = p1;
  }
  // x1 column partial sums (wave reads are fully coalesced: 64 lanes = 64 cols)
  {
    const float* xc = x1 + ((size_t)(b * NSEQ) + a * 64 + cb * 16) * NDIM + i64;
    float cs = 0.f;
#pragma unroll
    for (int i = 0; i < 16; ++i) cs += xc[i * NDIM];
    red[cb][i64] = cs;
  }
  __syncthreads();

  // kv^T GEMM: wave w covers k-feats [w*16,w*16+16) and v-feats likewise.
  f32x4 acck[4], accv[4];
#pragma unroll
  for (int i = 0; i < 4; ++i) {
    acck[i] = (f32x4){0.f, 0.f, 0.f, 0.f};
    accv[i] = (f32x4){0.f, 0.f, 0.f, 0.f};
  }
#pragma unroll
  for (int nt = 0; nt < 4; ++nt) {
    bf16x8 x0 = *(const bf16x8*)&xb[nt * 16 + lc][lr * 8];
    bf16x8 x1f = *(const bf16x8*)&xb[nt * 16 + lc][32 + lr * 8];
    acck[nt] = __builtin_amdgcn_mfma_f32_16x16x32_bf16(ak0, x0, acck[nt], 0, 0, 0);
    acck[nt] = __builtin_amdgcn_mfma_f32_16x16x32_bf16(ak1, x1f, acck[nt], 0, 0, 0);
    accv[nt] = __builtin_amdgcn_mfma_f32_16x16x32_bf16(av0, x0, accv[nt], 0, 0, 0);
    accv[nt] = __builtin_amdgcn_mfma_f32_16x16x32_bf16(av1, x1f, accv[nt], 0, 0, 0);
  }
  // C layout: row = feat = lr*4+j (within wave's 16), col = tok = nt*16+lc.
  // feat f = w*16+lr*4+j -> head = f>>3 = 2w + (lr>>1), in-head slot sb+j.
  const int head = 2 * w + (lr >> 1), sb = (lr & 1) * 4;
  {
    _Float16* kdst = (_Float16*)kvhk + ((size_t)(b * NH + head) * NSEQ) * 8 + sb;
    _Float16* vtb = (_Float16*)vt + ((size_t)(b * NH + head) * 9) * NSEQ;
#pragma unroll
    for (int nt = 0; nt < 4; ++nt) {
      const int tok = a * 64 + nt * 16 + lc;
      f16x4 pk4;
      pk4[0]=(_Float16)acck[nt][0]; pk4[1]=(_Float16)acck[nt][1];
      pk4[2]=(_Float16)acck[nt][2]; pk4[3]=(_Float16)acck[nt][3];
      *(f16x4*)(kdst + (size_t)tok * 8) = pk4;
#pragma unroll
      for (int j = 0; j < 4; ++j)
        vtb[(size_t)(sb + j) * NSEQ + tok] = (_Float16)accv[nt][j];
    }
  }

  // agent via mean-first (linearity of pooling): f32 all the way.
  if (t < 64) marr[t] = red[0][t] + red[1][t] + red[2][t] + red[3][t];
  __syncthreads();
  if (t < 64) {
    const float4* wqr = (const float4*)(Wq + (size_t)t * NDIM);
    const float4* mm = (const float4*)marr;
    float s0 = 0.f;
#pragma unroll
    for (int i = 0; i < 16; ++i) {
      float4 wv4 = wqr[i], m4 = mm[i];
      s0 += wv4.x * m4.x + wv4.y * m4.y + wv4.z * m4.z + wv4.w * m4.w;
    }
    const float val = s0 * (kScale * kLog2e / 64.f);
    const size_t idx = (((size_t)b * NH + (t >> 3)) * NAG + a) * 8 + (t & 7);
    agent[idx] = val;
    ((_Float16*)agf16)[idx] = (_Float16)val;
  }
}

// ---------------------------------------------------------------------------
// Kernel B: stage-0 attention via MFMA.
// Per (b,h), 32-token chunk:  S = K(16tok x 32dims[8 used]) x agent^T  (f16 MFMA,
// zero-padded B-groups kill garbage dims); P = exp2(S) packed f16; wave-private
// LDS relayout (no barriers); PV: O[agent][feat] += P^T x V'  where V' = V^T
// with a ones-row (feat 8) so the softmax denominator is output column 8.
// grid (8, 32, SPLIT), block 256 (4 waves). Per-z partials -> pvs_z (no atomics
// beyond LDS).
// ---------------------------------------------------------------------------
__global__ __launch_bounds__(256, 4) void stage0_kernel(
    const us* __restrict__ kvhk, const us* __restrict__ vt,
    const us* __restrict__ agf16, float* __restrict__ pvs_z) {
  __shared__ _Float16 pshuf[4][4][16][40]; // [wave][agtile][agent][tok32 pad->40] 20KB
  __shared__ float redS[64][12];           // 3KB
  const int h = blockIdx.x, b = blockIdx.y, z = blockIdx.z;
  const int t = threadIdx.x, l = t & 63, w = t >> 6;
  for (int i = t; i < 64 * 12; i += 256) (&redS[0][0])[i] = 0.f;

  const int lg = l >> 4, lm = l & 15;
  const size_t bh = (size_t)b * NH + h;
  const us* kb = kvhk + bh * ((size_t)NSEQ * 8);
  const us* vb = vt + bh * ((size_t)9 * NSEQ);
  const us* ab = agf16 + bh * (NAG * 8);

  // B_A frags (loop-invariant): B[k=dim lg*8+i][n=agent at*16+lm]; lg>0 -> 0
  f16x8 ba[4];
#pragma unroll
  for (int at = 0; at < 4; ++at) {
    f16x8 v = (f16x8)(_Float16)0.0f;
    if (lg == 0) {
      int row = at * 16 + lm; if (row > 48) row = 48;
      v = *(const f16x8*)(ab + row * 8);
    }
    ba[at] = v;
  }
  // B_V source: feat row lm (rows 9-15 clamp -> ones row 8), tokens lg*8+i
  const us* vrow = vb + (size_t)((lm > 8) ? 8 : lm) * NSEQ + lg * 8;

  f32x4 accPV[4];
#pragma unroll
  for (int i = 0; i < 4; ++i) accPV[i] = (f32x4){0.f, 0.f, 0.f, 0.f};

  _Float16* ps = &pshuf[w][0][0][0];
  const int iw = z * 4 + w;
  __syncthreads(); // redS zero visible before any epilogue atomics

  for (int c = iw; c < 98; c += SPLIT * 4) {
    // A_K frags (two 16-token halves); lg>0 reads neighbor-token data (finite),
    // killed by zeroed B_A groups.
    f16x8 aK0 = *(const f16x8*)(kb + ((size_t)c * 32 + lm) * 8 + lg * 8);
    f16x8 aK1 = *(const f16x8*)(kb + ((size_t)c * 32 + 16 + lm) * 8 + lg * 8);
    f16x8 bV = *(const f16x8*)(vrow + c * 32);
#pragma unroll
    for (int at = 0; at < 4; ++at) {
      f32x4 s0 = __builtin_amdgcn_mfma_f32_16x16x32_f16(
          aK0, ba[at], (f32x4){0.f, 0.f, 0.f, 0.f}, 0, 0, 0);
      f32x4 s1 = __builtin_amdgcn_mfma_f32_16x16x32_f16(
          aK1, ba[at], (f32x4){0.f, 0.f, 0.f, 0.f}, 0, 0, 0);
      // lane holds agent col lm, tokens half*16 + lg*4 + j
      unsigned p00 = pk2(fexp2(s0[0]), fexp2(s0[1]));
      unsigned p01 = pk2(fexp2(s0[2]), fexp2(s0[3]));
      unsigned p10 = pk2(fexp2(s1[0]), fexp2(s1[1]));
      unsigned p11 = pk2(fexp2(s1[2]), fexp2(s1[3]));
      unsigned long long q0 = ((unsigned long long)p01 << 32) | p00;
      unsigned long long q1 = ((unsigned long long)p11 << 32) | p10;
      _Float16* prow = ps + (size_t)(at * 16 + lm) * 40;
      *(unsigned long long*)(prow + lg * 4) = q0;        // tokens lg*4..+3
      *(unsigned long long*)(prow + 16 + lg * 4) = q1;   // tokens 16+lg*4..+3
    }
    // A_P frags: lane = agent lm (at-tile), tokens lg*8..+7 (same-wave LDS,
    // compiler inserts lgkmcnt)
#pragma unroll
    for (int at = 0; at < 4; ++at) {
      f16x8 aP = *(const f16x8*)(ps + (size_t)(at * 16 + lm) * 40 + lg * 8);
      accPV[at] = __builtin_amdgcn_mfma_f32_16x16x32_f16(aP, bV, accPV[at], 0, 0, 0);
    }
  }

  // epilogue: lane holds feat col lm (<9 used), agents at*16 + lg*4 + j
  if (lm < 9) {
#pragma unroll
    for (int at = 0; at < 4; ++at)
#pragma unroll
      for (int jj = 0; jj < 4; ++jj) {
        const int ag = at * 16 + lg * 4 + jj;
        if (ag < NAG) atomicAdd(&redS[ag][lm], accPV[at][jj]);
      }
  }
  __syncthreads();
  float* pz = pvs_z + ((size_t)z * (NB * NH) + bh) * (NAG * 12);
  for (int i = t; i < NAG * 9; i += 256) {
    pz[(i / 9) * 12 + (i % 9)] = redS[i / 9][i % 9];
  }
}

// ---------------------------------------------------------------------------
// Kernel C: stage-1 attention + output linear, fused.
// grid (49, 32), block 512 (8 waves). ao tables staged+normalized into LDS
// once per block (z-partials summed during staging); qld/catL merged.
// ---------------------------------------------------------------------------
__global__ __launch_bounds__(512, 6) void stage1_out_kernel(
    const float* __restrict__ x1, const __bf16* __restrict__ wq,
    const float* __restrict__ agent, const float* __restrict__ pvs_z,
    const __bf16* __restrict__ wo, const float* __restrict__ bo,
    float* __restrict__ out) {
  __shared__ __align__(16) __bf16 xa[64][72];     // 9216
  __shared__ __align__(16) __bf16 qcat[64][72];   // 9216 (q, then catL in-place)
  __shared__ __align__(16) float aot[392 * 20];   // 31360 ([agent8|pv/s 8|pad4])
  const int tile = blockIdx.x, b = blockIdx.y;
  const int t = threadIdx.x, tokl = t & 63, h = t >> 6;
  const int w = h, lr = (t >> 4) & 3, lc = t & 15;
  const int mtile = w & 3, thalf = w >> 2;

  // prefetch weight A-frags + bias (global; overlap with staging + barriers)
  bf16x8 wqf0 = *(const bf16x8*)(wq + (size_t)(mtile * 16 + lc) * NDIM + lr * 8);
  bf16x8 wqf1 = *(const bf16x8*)(wq + (size_t)(mtile * 16 + lc) * NDIM + 32 + lr * 8);
  bf16x8 wof[4];
#pragma unroll
  for (int ks = 0; ks < 4; ++ks)
    wof[ks] = *(const bf16x8*)(wo + (size_t)(w * 16 + lc) * 128 + ks * 32 + lr * 8);
  f32x4 bv = *(const f32x4*)(bo + w * 16 + lr * 4);

  // issue ao-table global loads early (written to LDS after q-GEMM)
  f32x4 ag0, ag1;
  f32x4 pvA = (f32x4){0.f,0.f,0.f,0.f}, pvB = (f32x4){0.f,0.f,0.f,0.f};
  float sden = 0.f;
  if (t < NH * NAG) {
    const int hi2 = t / NAG, ai = t - hi2 * NAG;
    const float* ap = agent + (((size_t)b * NH + hi2) * NAG + ai) * 8;
    ag0 = *(const f32x4*)ap; ag1 = *(const f32x4*)(ap + 4);
#pragma unroll
    for (int zz = 0; zz < SPLIT; ++zz) {
      const float* pp = pvs_z +
          (((size_t)zz * (NB * NH) + (size_t)b * NH + hi2) * NAG + ai) * 12;
      pvA += *(const f32x4*)pp;
      pvB += *(const f32x4*)(pp + 4);
      sden += pp[8];
    }
  }

  // stage x1 tile bf16 (thread: token tokl, cols h*8..h*8+7)
  {
    const float4* src = (const float4*)(x1 + ((size_t)b * NSEQ + tile * 64 + tokl) * NDIM + h * 8);
    float4 v0 = src[0], v1 = src[1];
    bf16x8 p;
    p[0]=(__bf16)v0.x; p[1]=(__bf16)v0.y; p[2]=(__bf16)v0.z; p[3]=(__bf16)v0.w;
    p[4]=(__bf16)v1.x; p[5]=(__bf16)v1.y; p[6]=(__bf16)v1.z; p[7]=(__bf16)v1.w;
    *(bf16x8*)&xa[tokl][h * 8] = p;
  }
  __syncthreads();

  // q^T = Wq @ x1^T (wave w: feat tile mtile, token half thalf) -> qcat bf16
  {
    f32x4 aq[2];
    aq[0] = (f32x4){0.f,0.f,0.f,0.f}; aq[1] = (f32x4){0.f,0.f,0.f,0.f};
#pragma unroll
    for (int nt = 0; nt < 2; ++nt) {
      bf16x8 bx0 = *(const bf16x8*)&xa[thalf * 32 + nt * 16 + lc][lr * 8];
      bf16x8 bx1 = *(const bf16x8*)&xa[thalf * 32 + nt * 16 + lc][32 + lr * 8];
      aq[nt] = __builtin_amdgcn_mfma_f32_16x16x32_bf16(wqf0, bx0, aq[nt], 0, 0, 0);
      aq[nt] = __builtin_amdgcn_mfma_f32_16x16x32_bf16(wqf1, bx1, aq[nt], 0, 0, 0);
    }
#pragma unroll
    for (int nt = 0; nt < 2; ++nt) {
      bf16x4 pk;
      pk[0]=(__bf16)aq[nt][0]; pk[1]=(__bf16)aq[nt][1];
      pk[2]=(__bf16)aq[nt][2]; pk[3]=(__bf16)aq[nt][3];
      *(bf16x4*)&qcat[thalf * 32 + nt * 16 + lc][mtile * 16 + lr * 4] = pk;
    }
  }
  // ao table -> LDS, normalized during staging (1 rcp per row, off hot loop)
  if (t < NH * NAG) {
    float inv = frcp(sden);
    float* dst = aot + t * 20;
    *(f32x4*)dst = ag0;
    *(f32x4*)(dst + 4) = ag1;
    *(f32x4*)(dst + 8)  = pvA * inv;
    *(f32x4*)(dst + 12) = pvB * inv;
  }
  __syncthreads();

  // stage-1 attention: thread = (tokl, h); table reads are LDS broadcasts
  {
    uint4 qv = *(const uint4*)&qcat[tokl][h * 8];
    f32x2 q01 = up2(qv.x), q23 = up2(qv.y), q45 = up2(qv.z), q67 = up2(qv.w);
    const float* hrow = aot + h * (NAG * 20);
    float s = 0.f;
    f32x2 o01 = {0.f,0.f}, o23 = {0.f,0.f}, o45 = {0.f,0.f}, o67 = {0.f,0.f};
#pragma unroll 7
    for (int a2 = 0; a2 < NAG; ++a2) {
      const float* r = hrow + a2 * 20;
      f32x4 A0 = *(const f32x4*)r,        A1 = *(const f32x4*)(r + 4);
      f32x4 P0 = *(const f32x4*)(r + 8),  P1 = *(const f32x4*)(r + 12);
      f32x2 d = q01 * (f32x2){A0[0], A0[1]};
      d += q23 * (f32x2){A0[2], A0[3]};
      d += q45 * (f32x2){A1[0], A1[1]};
      d += q67 * (f32x2){A1[2], A1[3]};
      float p = fexp2(d[0] + d[1]);
      s += p;
      f32x2 pp = {p, p};
      o01 += pp * (f32x2){P0[0], P0[1]}; o23 += pp * (f32x2){P0[2], P0[3]};
      o45 += pp * (f32x2){P1[0], P1[1]}; o67 += pp * (f32x2){P1[2], P1[3]};
    }
    float inv = frcp(s);
    bf16x8 pc;
    pc[0]=(__bf16)(o01[0]*inv); pc[1]=(__bf16)(o01[1]*inv);
    pc[2]=(__bf16)(o23[0]*inv); pc[3]=(__bf16)(o23[1]*inv);
    pc[4]=(__bf16)(o45[0]*inv); pc[5]=(__bf16)(o45[1]*inv);
    pc[6]=(__bf16)(o67[0]*inv); pc[7]=(__bf16)(o67[1]*inv);
    *(bf16x8*)&qcat[tokl][h * 8] = pc; // owner-thread slot: read q, write catL
  }
  __syncthreads();

  // out^T = Wo @ [catL|xa]^T; direct stores (lane: 4 consecutive feats of 1 tok)
  {
    f32x4 acc[4];
#pragma unroll
    for (int i = 0; i < 4; ++i) acc[i] = (f32x4){0.f,0.f,0.f,0.f};
#pragma unroll
    for (int ks = 0; ks < 4; ++ks) {
#pragma unroll
      for (int nt = 0; nt < 4; ++nt) {
        bf16x8 bx = (ks < 2) ? *(const bf16x8*)&qcat[nt * 16 + lc][ks * 32 + lr * 8]
                             : *(const bf16x8*)&xa[nt * 16 + lc][(ks - 2) * 32 + lr * 8];
        acc[nt] = __builtin_amdgcn_mfma_f32_16x16x32_bf16(wof[ks], bx, acc[nt], 0, 0, 0);
      }
    }
#pragma unroll
    for (int nt = 0; nt < 4; ++nt) {
      f32x4 v = acc[nt] + bv;
      float* dst = out + ((size_t)b * NSEQ + tile * 64 + nt * 16 + lc) * 128 + w * 16 + lr * 4;
      *(f32x4*)dst = v;
    }
  }
}

extern "C" void kernel_launch(void* const* d_in, const int* in_sizes, int n_in,
                              void* d_out, int out_size, void* d_ws, size_t ws_size,
                              hipStream_t stream) {
  (void)in_sizes; (void)n_in; (void)out_size; (void)ws_size;
  const float* x1 = (const float*)d_in[0];
  const float* x2 = (const float*)d_in[1];
  const float* Wq = (const float*)d_in[2];
  const float* Wk = (const float*)d_in[3];
  const float* Wv = (const float*)d_in[4];
  const float* Wo = (const float*)d_in[5];
  const float* bo = (const float*)d_in[6];
  float* out = (float*)d_out;

  us* vt = (us*)d_ws;                                      // 32*8*9*3136 f16 = 14.45MB
  us* kvhk = vt + (size_t)NB * NH * 9 * NSEQ;              // 32*8*3136*8 f16 (+32 pad)
  float* agent = (float*)(kvhk + (size_t)NB * NH * NSEQ * 8 + 32);
  us* agf16 = (us*)(agent + (size_t)NB * NH * NAG * 8);
  float* pvs_z = (float*)(agf16 + (size_t)NB * NH * NAG * 8);
  __bf16* wq_bf = (__bf16*)(pvs_z + (size_t)SPLIT * NB * NH * NAG * 12);
  __bf16* wk_bf = wq_bf + 4096;
  __bf16* wv_bf = wk_bf + 4096;
  __bf16* wo_bf = wv_bf + 4096;
  // total ws ~= 30.4 MB

  prep_kernel<<<dim3(64), 256, 0, stream>>>(Wq, Wk, Wv, Wo, wq_bf, wk_bf, wv_bf,
                                            wo_bf, kvhk, vt);
  qkv_agent_kernel<<<dim3(NAG, NB), 256, 0, stream>>>(x1, x2, Wq, wk_bf, wv_bf,
                                                      kvhk, vt, agent, agf16);
  stage0_kernel<<<dim3(NH, NB, SPLIT), 256, 0, stream>>>(kvhk, vt, agf16, pvs_z);
  stage1_out_kernel<<<dim3(NAG, NB), 512, 0, stream>>>(x1, wq_bf, agent, pvs_z,
                                                       wo_bf, bo, out);
}

// Round 6
// 79.693 us; speedup vs baseline: 1.3536x; 1.0823x over previous
//
#include <hip/hip_runtime.h>
#include <hip/hip_bf16.h>

#define NB 32
#define NSEQ 3136
#define NDIM 64
#define NH 8
#define NAG 49
#define SPLIT 4

static constexpr float kScale = 0.35355339059327378f; // 8^-0.5
static constexpr float kLog2e = 1.4426950408889634f;

typedef unsigned short us;
typedef __attribute__((ext_vector_type(8))) __bf16 bf16x8;
typedef __attribute__((ext_vector_type(2))) _Float16 f16x2;
typedef __attribute__((ext_vector_type(4))) _Float16 f16x4;
typedef __attribute__((ext_vector_type(8))) _Float16 f16x8;
typedef __attribute__((ext_vector_type(4))) float f32x4;
typedef __attribute__((ext_vector_type(2))) float f32x2;

__device__ __forceinline__ float fexp2(float x) {
#if __has_builtin(__builtin_amdgcn_exp2f)
  return __builtin_amdgcn_exp2f(x);
#else
  return exp2f(x);
#endif
}

__device__ __forceinline__ float frcp(float x) {
#if __has_builtin(__builtin_amdgcn_rcpf)
  return __builtin_amdgcn_rcpf(x);
#else
  return 1.f / x;
#endif
}

__device__ __forceinline__ unsigned pk2(float a, float b) { // pack 2 f32 -> f16x2
#if __has_builtin(__builtin_amdgcn_cvt_pkrtz)
  return __builtin_bit_cast(unsigned, __builtin_amdgcn_cvt_pkrtz(a, b));
#else
  f16x2 v = {(_Float16)a, (_Float16)b};
  return __builtin_bit_cast(unsigned, v);
#endif
}

__device__ __forceinline__ f16x2 bch(unsigned u) { return __builtin_bit_cast(f16x2, u); }

// ---------------------------------------------------------------------------
// Kernel P: weights -> bf16; zero kvhk tail pad; vt "ones" row (feat 8) per bh.
// ---------------------------------------------------------------------------
__global__ __launch_bounds__(256) void prep_kernel(
    const float* __restrict__ Wq, const float* __restrict__ Wk,
    const float* __restrict__ Wv, const float* __restrict__ Wo,
    __bf16* __restrict__ wq, __bf16* __restrict__ wk, __bf16* __restrict__ wv,
    __bf16* __restrict__ wo, us* __restrict__ kvhk, us* __restrict__ vt) {
  int i = blockIdx.x * 256 + threadIdx.x; // 64 blocks -> 16384
  wo[i] = (__bf16)Wo[i];
  if (i < 4096) { wq[i] = (__bf16)Wq[i]; wk[i] = (__bf16)Wk[i]; wv[i] = (__bf16)Wv[i]; }
  if (i < 32) kvhk[(size_t)NB * NH * NSEQ * 8 + i] = 0;
  const us one = 0x3C00; // f16 1.0
  for (size_t j = i; j < (size_t)NB * NH * NSEQ; j += 16384) {
    size_t bh = j / NSEQ, tok = j - bh * NSEQ;
    vt[(bh * 9 + 8) * NSEQ + tok] = one;
  }
}

// ---------------------------------------------------------------------------
// Kernel A: kv^T GEMM (swapped MFMA operands). Outputs:
//   kvhk[b,h][tok][8]   k f16 (row-contig, +32 f16 zero pad at end)
//   vt  [b,h][9][3136]  V^T f16 via LDS-transpose + coalesced 16B stores
//   agf16 (f16) = log2e*kScale*(colsum(x1)/64) @ Wq^T
// grid (49,32), block 256 (4 waves).
// ---------------------------------------------------------------------------
__global__ __launch_bounds__(256, 4) void qkv_agent_kernel(
    const float* __restrict__ x1, const float* __restrict__ x2,
    const float* __restrict__ Wq, const __bf16* __restrict__ wk,
    const __bf16* __restrict__ wv, us* __restrict__ kvhk, us* __restrict__ vt,
    us* __restrict__ agf16) {
  __shared__ __align__(16) __bf16 xb[64][72];
  __shared__ __align__(16) float red[4][64];
  __shared__ __align__(16) float marr[64];
  const int a = blockIdx.x, b = blockIdx.y, t = threadIdx.x;
  const int i64 = t & 63, cb = t >> 6;
  const int w = cb, lr = (t >> 4) & 3, lc = t & 15;

  // prefetch A-frags (W rows; independent of LDS, overlaps staging)
  bf16x8 ak0 = *(const bf16x8*)(wk + (size_t)(w * 16 + lc) * NDIM + lr * 8);
  bf16x8 ak1 = *(const bf16x8*)(wk + (size_t)(w * 16 + lc) * NDIM + 32 + lr * 8);
  bf16x8 av0 = *(const bf16x8*)(wv + (size_t)(w * 16 + lc) * NDIM + lr * 8);
  bf16x8 av1 = *(const bf16x8*)(wv + (size_t)(w * 16 + lc) * NDIM + 32 + lr * 8);

  // stage x2 tile as bf16 (thread: one row, 16 cols)
  {
    const float4* s2 = (const float4*)(x2 + ((size_t)(b * NSEQ) + a * 64 + i64) * NDIM + cb * 16);
    float4 v0 = s2[0], v1 = s2[1], v2 = s2[2], v3 = s2[3];
    bf16x8 p0, p1;
    p0[0]=(__bf16)v0.x; p0[1]=(__bf16)v0.y; p0[2]=(__bf16)v0.z; p0[3]=(__bf16)v0.w;
    p0[4]=(__bf16)v1.x; p0[5]=(__bf16)v1.y; p0[6]=(__bf16)v1.z; p0[7]=(__bf16)v1.w;
    p1[0]=(__bf16)v2.x; p1[1]=(__bf16)v2.y; p1[2]=(__bf16)v2.z; p1[3]=(__bf16)v2.w;
    p1[4]=(__bf16)v3.x; p1[5]=(__bf16)v3.y; p1[6]=(__bf16)v3.z; p1[7]=(__bf16)v3.w;
    *(bf16x8*)&xb[i64][cb * 16] = p0; *(bf16x8*)&xb[i64][cb * 16 + 8] = p1;
  }
  // x1 column partial sums (wave reads are fully coalesced: 64 lanes = 64 cols)
  {
    const float* xc = x1 + ((size_t)(b * NSEQ) + a * 64 + cb * 16) * NDIM + i64;
    float cs = 0.f;
#pragma unroll
    for (int i = 0; i < 16; ++i) cs += xc[i * NDIM];
    red[cb][i64] = cs;
  }
  __syncthreads();

  // kv^T GEMM: wave w covers k-feats [w*16,w*16+16) and v-feats likewise.
  f32x4 acck[4], accv[4];
#pragma unroll
  for (int i = 0; i < 4; ++i) {
    acck[i] = (f32x4){0.f, 0.f, 0.f, 0.f};
    accv[i] = (f32x4){0.f, 0.f, 0.f, 0.f};
  }
#pragma unroll
  for (int nt = 0; nt < 4; ++nt) {
    bf16x8 x0 = *(const bf16x8*)&xb[nt * 16 + lc][lr * 8];
    bf16x8 x1f = *(const bf16x8*)&xb[nt * 16 + lc][32 + lr * 8];
    acck[nt] = __builtin_amdgcn_mfma_f32_16x16x32_bf16(ak0, x0, acck[nt], 0, 0, 0);
    acck[nt] = __builtin_amdgcn_mfma_f32_16x16x32_bf16(ak1, x1f, acck[nt], 0, 0, 0);
    accv[nt] = __builtin_amdgcn_mfma_f32_16x16x32_bf16(av0, x0, accv[nt], 0, 0, 0);
    accv[nt] = __builtin_amdgcn_mfma_f32_16x16x32_bf16(av1, x1f, accv[nt], 0, 0, 0);
  }
  // k stores (coalesced): feat f = w*16+lr*4+j -> head 2w+(lr>>1), slot (lr&1)*4+j
  const int head = 2 * w + (lr >> 1), sb = (lr & 1) * 4;
  {
    _Float16* kdst = (_Float16*)kvhk + ((size_t)(b * NH + head) * NSEQ) * 8 + sb;
#pragma unroll
    for (int nt = 0; nt < 4; ++nt) {
      const int tok = a * 64 + nt * 16 + lc;
      f16x4 pk4;
      pk4[0]=(_Float16)acck[nt][0]; pk4[1]=(_Float16)acck[nt][1];
      pk4[2]=(_Float16)acck[nt][2]; pk4[3]=(_Float16)acck[nt][3];
      *(f16x4*)(kdst + (size_t)tok * 8) = pk4;
    }
  }
  __syncthreads(); // all xb GEMM reads done -> overlay vtile on xb

  _Float16 (*vtile)[72] = (_Float16(*)[72])xb; // 64x72 f16 = 9216B, 16B rows
  {
    const int f0 = w * 16 + lr * 4;
#pragma unroll
    for (int nt = 0; nt < 4; ++nt) {
      const int tok = nt * 16 + lc;
#pragma unroll
      for (int j = 0; j < 4; ++j) vtile[f0 + j][tok] = (_Float16)accv[nt][j];
    }
  }
  if (t < 64) marr[t] = red[0][t] + red[1][t] + red[2][t] + red[3][t];
  __syncthreads();

  // coalesced V^T stores: thread -> row r (feat), piece p (16 tokens = 32B)
  {
    const int r = t >> 2, p = t & 3;
    _Float16* drow = (_Float16*)vt +
        ((size_t)(b * NH + (r >> 3)) * 9 + (r & 7)) * NSEQ + a * 64 + p * 16;
    f16x8 v0 = *(const f16x8*)&vtile[r][p * 16];
    f16x8 v1 = *(const f16x8*)&vtile[r][p * 16 + 8];
    *(f16x8*)drow = v0;
    *(f16x8*)(drow + 8) = v1;
  }
  // agent via mean-first (linearity of pooling), f32 math -> f16 store
  if (t < 64) {
    const float4* wqr = (const float4*)(Wq + (size_t)t * NDIM);
    const float4* mm = (const float4*)marr;
    float s0 = 0.f;
#pragma unroll
    for (int i = 0; i < 16; ++i) {
      float4 wv4 = wqr[i], m4 = mm[i];
      s0 += wv4.x * m4.x + wv4.y * m4.y + wv4.z * m4.z + wv4.w * m4.w;
    }
    const float val = s0 * (kScale * kLog2e / 64.f);
    ((_Float16*)agf16)[(((size_t)b * NH + (t >> 3)) * NAG + a) * 8 + (t & 7)] =
        (_Float16)val;
  }
}

// ---------------------------------------------------------------------------
// Kernel B: stage-0 attention via MFMA, with next-chunk register prefetch.
// grid (8, 32, SPLIT), block 256 (4 waves). Per-z partials -> pvs_z.
// ---------------------------------------------------------------------------
__global__ __launch_bounds__(256, 4) void stage0_kernel(
    const us* __restrict__ kvhk, const us* __restrict__ vt,
    const us* __restrict__ agf16, float* __restrict__ pvs_z) {
  __shared__ _Float16 pshuf[4][4][16][40]; // [wave][agtile][agent][tok32 pad] 20KB
  __shared__ float redS[64][12];           // 3KB
  const int h = blockIdx.x, b = blockIdx.y, z = blockIdx.z;
  const int t = threadIdx.x, l = t & 63, w = t >> 6;
  for (int i = t; i < 64 * 12; i += 256) (&redS[0][0])[i] = 0.f;

  const int lg = l >> 4, lm = l & 15;
  const size_t bh = (size_t)b * NH + h;
  const us* kb = kvhk + bh * ((size_t)NSEQ * 8);
  const us* vb = vt + bh * ((size_t)9 * NSEQ);
  const us* ab = agf16 + bh * (NAG * 8);

  // B_A frags (loop-invariant): agent cols; lg>0 zeroed (kills pad dims)
  f16x8 ba[4];
#pragma unroll
  for (int at = 0; at < 4; ++at) {
    f16x8 v = (f16x8)(_Float16)0.0f;
    if (lg == 0) {
      int row = at * 16 + lm; if (row > 48) row = 48;
      v = *(const f16x8*)(ab + row * 8);
    }
    ba[at] = v;
  }
  const us* vrow = vb + (size_t)((lm > 8) ? 8 : lm) * NSEQ + lg * 8;

  f32x4 accPV[4];
#pragma unroll
  for (int i = 0; i < 4; ++i) accPV[i] = (f32x4){0.f, 0.f, 0.f, 0.f};

  _Float16* ps = &pshuf[w][0][0][0];
  const int iw = z * 4 + w;
  __syncthreads(); // redS zero visible before any epilogue atomics

  f16x8 aK0, aK1, bV;
  aK0 = *(const f16x8*)(kb + ((size_t)iw * 32 + lm) * 8 + lg * 8);
  aK1 = *(const f16x8*)(kb + ((size_t)iw * 32 + 16 + lm) * 8 + lg * 8);
  bV  = *(const f16x8*)(vrow + iw * 32);

  for (int c = iw; c < 98; c += 16) {
    f16x8 nK0, nK1, nV;
    const int cn = c + 16;
    if (cn < 98) { // prefetch next chunk (covers L2 latency under MFMAs)
      nK0 = *(const f16x8*)(kb + ((size_t)cn * 32 + lm) * 8 + lg * 8);
      nK1 = *(const f16x8*)(kb + ((size_t)cn * 32 + 16 + lm) * 8 + lg * 8);
      nV  = *(const f16x8*)(vrow + cn * 32);
    }
#pragma unroll
    for (int at = 0; at < 4; ++at) {
      f32x4 s0 = __builtin_amdgcn_mfma_f32_16x16x32_f16(
          aK0, ba[at], (f32x4){0.f, 0.f, 0.f, 0.f}, 0, 0, 0);
      f32x4 s1 = __builtin_amdgcn_mfma_f32_16x16x32_f16(
          aK1, ba[at], (f32x4){0.f, 0.f, 0.f, 0.f}, 0, 0, 0);
      unsigned p00 = pk2(fexp2(s0[0]), fexp2(s0[1]));
      unsigned p01 = pk2(fexp2(s0[2]), fexp2(s0[3]));
      unsigned p10 = pk2(fexp2(s1[0]), fexp2(s1[1]));
      unsigned p11 = pk2(fexp2(s1[2]), fexp2(s1[3]));
      unsigned long long q0 = ((unsigned long long)p01 << 32) | p00;
      unsigned long long q1 = ((unsigned long long)p11 << 32) | p10;
      _Float16* prow = ps + (size_t)(at * 16 + lm) * 40;
      *(unsigned long long*)(prow + lg * 4) = q0;
      *(unsigned long long*)(prow + 16 + lg * 4) = q1;
    }
#pragma unroll
    for (int at = 0; at < 4; ++at) {
      f16x8 aP = *(const f16x8*)(ps + (size_t)(at * 16 + lm) * 40 + lg * 8);
      accPV[at] = __builtin_amdgcn_mfma_f32_16x16x32_f16(aP, bV, accPV[at], 0, 0, 0);
    }
    aK0 = nK0; aK1 = nK1; bV = nV;
  }

  // epilogue: lane holds feat col lm (<9 used), agents at*16 + lg*4 + j
  if (lm < 9) {
#pragma unroll
    for (int at = 0; at < 4; ++at)
#pragma unroll
      for (int jj = 0; jj < 4; ++jj) {
        const int ag = at * 16 + lg * 4 + jj;
        if (ag < NAG) atomicAdd(&redS[ag][lm], accPV[at][jj]);
      }
  }
  __syncthreads();
  float* pz = pvs_z + ((size_t)z * (NB * NH) + bh) * (NAG * 12);
  for (int i = t; i < NAG * 9; i += 256) {
    pz[(i / 9) * 12 + (i % 9)] = redS[i / 9][i % 9];
  }
}

// ---------------------------------------------------------------------------
// Kernel D: finalize ao table ONCE per (b,h,a): z-sum + rcp + f16 pack.
// aof16[b,h,a][16] = [agent f16 x8 | pv*inv f16 x8]. grid (NH,NB), 64 thr.
// ---------------------------------------------------------------------------
__global__ __launch_bounds__(64) void aofin_kernel(
    const us* __restrict__ agf16, const float* __restrict__ pvs_z,
    us* __restrict__ aof16) {
  const int h = blockIdx.x, b = blockIdx.y, t = threadIdx.x;
  if (t >= NAG) return;
  const size_t bh = (size_t)b * NH + h;
  f32x4 pv0 = (f32x4){0.f,0.f,0.f,0.f}, pv1 = (f32x4){0.f,0.f,0.f,0.f};
  float den = 0.f;
#pragma unroll
  for (int zz = 0; zz < SPLIT; ++zz) {
    const float* pp = pvs_z + (((size_t)zz * (NB * NH) + bh) * NAG + t) * 12;
    pv0 += *(const f32x4*)pp;
    pv1 += *(const f32x4*)(pp + 4);
    den += pp[8];
  }
  float inv = frcp(den);
  pv0 *= inv; pv1 *= inv;
  us* dst = aof16 + (bh * NAG + t) * 16;
  *(uint4*)dst = *(const uint4*)(agf16 + (bh * NAG + t) * 8);
  f16x4 a, c;
  a[0]=(_Float16)pv0[0]; a[1]=(_Float16)pv0[1]; a[2]=(_Float16)pv0[2]; a[3]=(_Float16)pv0[3];
  c[0]=(_Float16)pv1[0]; c[1]=(_Float16)pv1[1]; c[2]=(_Float16)pv1[2]; c[3]=(_Float16)pv1[3];
  *(f16x4*)(dst + 8) = a;
  *(f16x4*)(dst + 12) = c;
}

// ---------------------------------------------------------------------------
// Kernel C: stage-1 attention + output linear, fused.
// grid (49, 32), block 512 (8 waves), 4 blocks/CU (LDS 31KB, VGPR<=64).
// f16 softmax datapath: 2x ds_read_b128 + 4 fdot2 + exp + 4 pk_fma_f16 / iter.
// ---------------------------------------------------------------------------
__global__ __launch_bounds__(512, 8) void stage1_out_kernel(
    const float* __restrict__ x1, const __bf16* __restrict__ wq,
    const us* __restrict__ aof16, const __bf16* __restrict__ wo,
    const float* __restrict__ bo, float* __restrict__ out) {
  __shared__ __align__(16) __bf16 xa[64][72];   // 9216
  __shared__ __align__(16) us qcat[64][72];     // 9216 (q f16, then catL bf16)
  __shared__ __align__(16) us aof[392 * 16];    // 12544
  const int tile = blockIdx.x, b = blockIdx.y;
  const int t = threadIdx.x, tokl = t & 63, h = t >> 6;
  const int w = h, lr = (t >> 4) & 3, lc = t & 15;
  const int mtile = w & 3, thalf = w >> 2;

  // prefetch q-weight frags (overlap with staging)
  bf16x8 wqf0 = *(const bf16x8*)(wq + (size_t)(mtile * 16 + lc) * NDIM + lr * 8);
  bf16x8 wqf1 = *(const bf16x8*)(wq + (size_t)(mtile * 16 + lc) * NDIM + 32 + lr * 8);

  // stage x1 tile bf16 (thread: token tokl, cols h*8..h*8+7)
  {
    const float4* src = (const float4*)(x1 + ((size_t)b * NSEQ + tile * 64 + tokl) * NDIM + h * 8);
    float4 v0 = src[0], v1 = src[1];
    bf16x8 p;
    p[0]=(__bf16)v0.x; p[1]=(__bf16)v0.y; p[2]=(__bf16)v0.z; p[3]=(__bf16)v0.w;
    p[4]=(__bf16)v1.x; p[5]=(__bf16)v1.y; p[6]=(__bf16)v1.z; p[7]=(__bf16)v1.w;
    *(bf16x8*)&xa[tokl][h * 8] = p;
  }
  // ao table -> LDS (coalesced 12.5KB copy; aof16 precomputed by aofin)
  {
    const uint4* src = (const uint4*)(aof16 + (size_t)b * (NH * NAG * 16));
    uint4* dst = (uint4*)aof;
    for (int i = t; i < 784; i += 512) dst[i] = src[i];
  }
  __syncthreads();

  // q^T = Wq @ x1^T -> qcat as f16
  {
    f32x4 aq[2];
    aq[0] = (f32x4){0.f,0.f,0.f,0.f}; aq[1] = (f32x4){0.f,0.f,0.f,0.f};
#pragma unroll
    for (int nt = 0; nt < 2; ++nt) {
      bf16x8 bx0 = *(const bf16x8*)&xa[thalf * 32 + nt * 16 + lc][lr * 8];
      bf16x8 bx1 = *(const bf16x8*)&xa[thalf * 32 + nt * 16 + lc][32 + lr * 8];
      aq[nt] = __builtin_amdgcn_mfma_f32_16x16x32_bf16(wqf0, bx0, aq[nt], 0, 0, 0);
      aq[nt] = __builtin_amdgcn_mfma_f32_16x16x32_bf16(wqf1, bx1, aq[nt], 0, 0, 0);
    }
#pragma unroll
    for (int nt = 0; nt < 2; ++nt) {
      f16x4 pk;
      pk[0]=(_Float16)aq[nt][0]; pk[1]=(_Float16)aq[nt][1];
      pk[2]=(_Float16)aq[nt][2]; pk[3]=(_Float16)aq[nt][3];
      *(f16x4*)&qcat[thalf * 32 + nt * 16 + lc][mtile * 16 + lr * 4] = pk;
    }
  }
  __syncthreads();

  // stage-1 attention: thread = (tokl, h); f16 table rows are LDS broadcasts
  {
    uint4 qv = *(const uint4*)&qcat[tokl][h * 8];
    f16x2 q0 = bch(qv.x), q1 = bch(qv.y), q2 = bch(qv.z), q3 = bch(qv.w);
    const us* hrow = aof + (h * NAG) * 16;
    float s = 0.f;
    f16x2 o01 = (f16x2)(_Float16)0.f, o23 = o01, o45 = o01, o67 = o01;
#pragma unroll 7
    for (int a2 = 0; a2 < NAG; ++a2) {
      const us* r = hrow + a2 * 16;
      uint4 A = *(const uint4*)r;
      uint4 V = *(const uint4*)(r + 8);
      float lg;
#if __has_builtin(__builtin_amdgcn_fdot2)
      lg = __builtin_amdgcn_fdot2(q0, bch(A.x), 0.f, false);
      lg = __builtin_amdgcn_fdot2(q1, bch(A.y), lg, false);
      lg = __builtin_amdgcn_fdot2(q2, bch(A.z), lg, false);
      lg = __builtin_amdgcn_fdot2(q3, bch(A.w), lg, false);
#else
      f16x2 a0 = bch(A.x), a1 = bch(A.y), a2_ = bch(A.z), a3 = bch(A.w);
      lg = (float)q0[0]*(float)a0[0] + (float)q0[1]*(float)a0[1]
         + (float)q1[0]*(float)a1[0] + (float)q1[1]*(float)a1[1]
         + (float)q2[0]*(float)a2_[0] + (float)q2[1]*(float)a2_[1]
         + (float)q3[0]*(float)a3[0] + (float)q3[1]*(float)a3[1];
#endif
      float p = fexp2(lg);
      s += p;
      _Float16 pf = (_Float16)p;
      f16x2 pp = {pf, pf};
      o01 += pp * bch(V.x); o23 += pp * bch(V.y);
      o45 += pp * bch(V.z); o67 += pp * bch(V.w);
    }
    float inv = frcp(s);
    bf16x8 pc;
    pc[0]=(__bf16)((float)o01[0]*inv); pc[1]=(__bf16)((float)o01[1]*inv);
    pc[2]=(__bf16)((float)o23[0]*inv); pc[3]=(__bf16)((float)o23[1]*inv);
    pc[4]=(__bf16)((float)o45[0]*inv); pc[5]=(__bf16)((float)o45[1]*inv);
    pc[6]=(__bf16)((float)o67[0]*inv); pc[7]=(__bf16)((float)o67[1]*inv);
    *(bf16x8*)&qcat[tokl][h * 8] = pc; // owner-thread slot: read q, write catL
  }
  // load Wo frags + bias late (issue under the barrier wait; frees VGPRs above)
  bf16x8 wof[4];
#pragma unroll
  for (int ks = 0; ks < 4; ++ks)
    wof[ks] = *(const bf16x8*)(wo + (size_t)(w * 16 + lc) * 128 + ks * 32 + lr * 8);
  f32x4 bv = *(const f32x4*)(bo + w * 16 + lr * 4);
  __syncthreads();

  // out^T = Wo @ [catL|xa]^T; direct stores (lane: 4 consecutive feats of 1 tok)
  {
    f32x4 acc[4];
#pragma unroll
    for (int i = 0; i < 4; ++i) acc[i] = (f32x4){0.f,0.f,0.f,0.f};
#pragma unroll
    for (int ks = 0; ks < 4; ++ks) {
#pragma unroll
      for (int nt = 0; nt < 4; ++nt) {
        bf16x8 bx = (ks < 2) ? *(const bf16x8*)&qcat[nt * 16 + lc][ks * 32 + lr * 8]
                             : *(const bf16x8*)&xa[nt * 16 + lc][(ks - 2) * 32 + lr * 8];
        acc[nt] = __builtin_amdgcn_mfma_f32_16x16x32_bf16(wof[ks], bx, acc[nt], 0, 0, 0);
      }
    }
#pragma unroll
    for (int nt = 0; nt < 4; ++nt) {
      f32x4 v = acc[nt] + bv;
      float* dst = out + ((size_t)b * NSEQ + tile * 64 + nt * 16 + lc) * 128 + w * 16 + lr * 4;
      *(f32x4*)dst = v;
    }
  }
}

extern "C" void kernel_launch(void* const* d_in, const int* in_sizes, int n_in,
                              void* d_out, int out_size, void* d_ws, size_t ws_size,
                              hipStream_t stream) {
  (void)in_sizes; (void)n_in; (void)out_size; (void)ws_size;
  const float* x1 = (const float*)d_in[0];
  const float* x2 = (const float*)d_in[1];
  const float* Wq = (const float*)d_in[2];
  const float* Wk = (const float*)d_in[3];
  const float* Wv = (const float*)d_in[4];
  const float* Wo = (const float*)d_in[5];
  const float* bo = (const float*)d_in[6];
  float* out = (float*)d_out;

  us* vt = (us*)d_ws;                                      // 32*8*9*3136 f16 = 14.45MB
  us* kvhk = vt + (size_t)NB * NH * 9 * NSEQ;              // 32*8*3136*8 f16 (+32 pad)
  us* agf16 = kvhk + (size_t)NB * NH * NSEQ * 8 + 32;      // 100352 f16
  float* pvs_z = (float*)(agf16 + (size_t)NB * NH * NAG * 8);
  us* aof16 = (us*)(pvs_z + (size_t)SPLIT * NB * NH * NAG * 12);
  __bf16* wq_bf = (__bf16*)(aof16 + (size_t)NB * NH * NAG * 16);
  __bf16* wk_bf = wq_bf + 4096;
  __bf16* wv_bf = wk_bf + 4096;
  __bf16* wo_bf = wv_bf + 4096;
  // total ws ~= 30.5 MB

  prep_kernel<<<dim3(64), 256, 0, stream>>>(Wq, Wk, Wv, Wo, wq_bf, wk_bf, wv_bf,
                                            wo_bf, kvhk, vt);
  qkv_agent_kernel<<<dim3(NAG, NB), 256, 0, stream>>>(x1, x2, Wq, wk_bf, wv_bf,
                                                      kvhk, vt, agf16);
  stage0_kernel<<<dim3(NH, NB, SPLIT), 256, 0, stream>>>(kvhk, vt, agf16, pvs_z);
  aofin_kernel<<<dim3(NH, NB), 64, 0, stream>>>(agf16, pvs_z, aof16);
  stage1_out_kernel<<<dim3(NAG, NB), 512, 0, stream>>>(x1, wq_bf, aof16, wo_bf,
                                                       bo, out);
}

// Round 7
// 79.479 us; speedup vs baseline: 1.3573x; 1.0027x over previous
//
#include <hip/hip_runtime.h>
#include <hip/hip_bf16.h>

#define NB 32
#define NSEQ 3136
#define NDIM 64
#define NH 8
#define NAG 49
#define SPLIT 4

static constexpr float kScale = 0.35355339059327378f; // 8^-0.5
static constexpr float kLog2e = 1.4426950408889634f;

typedef unsigned short us;
typedef __attribute__((ext_vector_type(8))) __bf16 bf16x8;
typedef __attribute__((ext_vector_type(2))) _Float16 f16x2;
typedef __attribute__((ext_vector_type(4))) _Float16 f16x4;
typedef __attribute__((ext_vector_type(8))) _Float16 f16x8;
typedef __attribute__((ext_vector_type(4))) float f32x4;
typedef __attribute__((ext_vector_type(2))) float f32x2;

__device__ __forceinline__ float fexp2(float x) {
#if __has_builtin(__builtin_amdgcn_exp2f)
  return __builtin_amdgcn_exp2f(x);
#else
  return exp2f(x);
#endif
}

__device__ __forceinline__ float frcp(float x) {
#if __has_builtin(__builtin_amdgcn_rcpf)
  return __builtin_amdgcn_rcpf(x);
#else
  return 1.f / x;
#endif
}

__device__ __forceinline__ unsigned pk2(float a, float b) { // pack 2 f32 -> f16x2
#if __has_builtin(__builtin_amdgcn_cvt_pkrtz)
  return __builtin_bit_cast(unsigned, __builtin_amdgcn_cvt_pkrtz(a, b));
#else
  f16x2 v = {(_Float16)a, (_Float16)b};
  return __builtin_bit_cast(unsigned, v);
#endif
}

// ---------------------------------------------------------------------------
// Kernel P: weights -> bf16; zero kvhk tail pad; vt "ones" row (feat 8) per bh.
// ---------------------------------------------------------------------------
__global__ __launch_bounds__(256) void prep_kernel(
    const float* __restrict__ Wq, const float* __restrict__ Wk,
    const float* __restrict__ Wv, const float* __restrict__ Wo,
    __bf16* __restrict__ wq, __bf16* __restrict__ wk, __bf16* __restrict__ wv,
    __bf16* __restrict__ wo, us* __restrict__ kvhk, us* __restrict__ vt) {
  int i = blockIdx.x * 256 + threadIdx.x; // 64 blocks -> 16384
  wo[i] = (__bf16)Wo[i];
  if (i < 4096) { wq[i] = (__bf16)Wq[i]; wk[i] = (__bf16)Wk[i]; wv[i] = (__bf16)Wv[i]; }
  if (i < 32) kvhk[(size_t)NB * NH * NSEQ * 8 + i] = 0;
  const us one = 0x3C00; // f16 1.0
  for (size_t j = i; j < (size_t)NB * NH * NSEQ; j += 16384) {
    size_t bh = j / NSEQ, tok = j - bh * NSEQ;
    vt[(bh * 9 + 8) * NSEQ + tok] = one;
  }
}

// ---------------------------------------------------------------------------
// Kernel A: kv^T GEMM (swapped MFMA operands). Outputs:
//   kvhk[b,h][tok][8]   k f16 (row-contig, +32 f16 zero pad at end)
//   vt  [b,h][9][3136]  V^T f16 via LDS-transpose + coalesced 16B stores
//   agf16 (f16) = log2e*kScale*(colsum(x1)/64) @ Wq^T
// grid (49,32), block 256 (4 waves).
// ---------------------------------------------------------------------------
__global__ __launch_bounds__(256, 4) void qkv_agent_kernel(
    const float* __restrict__ x1, const float* __restrict__ x2,
    const float* __restrict__ Wq, const __bf16* __restrict__ wk,
    const __bf16* __restrict__ wv, us* __restrict__ kvhk, us* __restrict__ vt,
    us* __restrict__ agf16) {
  __shared__ __align__(16) __bf16 xb[64][72];
  __shared__ __align__(16) float red[4][64];
  __shared__ __align__(16) float marr[64];
  const int a = blockIdx.x, b = blockIdx.y, t = threadIdx.x;
  const int i64 = t & 63, cb = t >> 6;
  const int w = cb, lr = (t >> 4) & 3, lc = t & 15;

  // prefetch A-frags (W rows; independent of LDS, overlaps staging)
  bf16x8 ak0 = *(const bf16x8*)(wk + (size_t)(w * 16 + lc) * NDIM + lr * 8);
  bf16x8 ak1 = *(const bf16x8*)(wk + (size_t)(w * 16 + lc) * NDIM + 32 + lr * 8);
  bf16x8 av0 = *(const bf16x8*)(wv + (size_t)(w * 16 + lc) * NDIM + lr * 8);
  bf16x8 av1 = *(const bf16x8*)(wv + (size_t)(w * 16 + lc) * NDIM + 32 + lr * 8);

  // stage x2 tile as bf16 (thread: one row, 16 cols)
  {
    const float4* s2 = (const float4*)(x2 + ((size_t)(b * NSEQ) + a * 64 + i64) * NDIM + cb * 16);
    float4 v0 = s2[0], v1 = s2[1], v2 = s2[2], v3 = s2[3];
    bf16x8 p0, p1;
    p0[0]=(__bf16)v0.x; p0[1]=(__bf16)v0.y; p0[2]=(__bf16)v0.z; p0[3]=(__bf16)v0.w;
    p0[4]=(__bf16)v1.x; p0[5]=(__bf16)v1.y; p0[6]=(__bf16)v1.z; p0[7]=(__bf16)v1.w;
    p1[0]=(__bf16)v2.x; p1[1]=(__bf16)v2.y; p1[2]=(__bf16)v2.z; p1[3]=(__bf16)v2.w;
    p1[4]=(__bf16)v3.x; p1[5]=(__bf16)v3.y; p1[6]=(__bf16)v3.z; p1[7]=(__bf16)v3.w;
    *(bf16x8*)&xb[i64][cb * 16] = p0; *(bf16x8*)&xb[i64][cb * 16 + 8] = p1;
  }
  // x1 column partial sums (wave reads are fully coalesced: 64 lanes = 64 cols)
  {
    const float* xc = x1 + ((size_t)(b * NSEQ) + a * 64 + cb * 16) * NDIM + i64;
    float cs = 0.f;
#pragma unroll
    for (int i = 0; i < 16; ++i) cs += xc[i * NDIM];
    red[cb][i64] = cs;
  }
  __syncthreads();

  // kv^T GEMM: wave w covers k-feats [w*16,w*16+16) and v-feats likewise.
  f32x4 acck[4], accv[4];
#pragma unroll
  for (int i = 0; i < 4; ++i) {
    acck[i] = (f32x4){0.f, 0.f, 0.f, 0.f};
    accv[i] = (f32x4){0.f, 0.f, 0.f, 0.f};
  }
#pragma unroll
  for (int nt = 0; nt < 4; ++nt) {
    bf16x8 x0 = *(const bf16x8*)&xb[nt * 16 + lc][lr * 8];
    bf16x8 x1f = *(const bf16x8*)&xb[nt * 16 + lc][32 + lr * 8];
    acck[nt] = __builtin_amdgcn_mfma_f32_16x16x32_bf16(ak0, x0, acck[nt], 0, 0, 0);
    acck[nt] = __builtin_amdgcn_mfma_f32_16x16x32_bf16(ak1, x1f, acck[nt], 0, 0, 0);
    accv[nt] = __builtin_amdgcn_mfma_f32_16x16x32_bf16(av0, x0, accv[nt], 0, 0, 0);
    accv[nt] = __builtin_amdgcn_mfma_f32_16x16x32_bf16(av1, x1f, accv[nt], 0, 0, 0);
  }
  // k stores (coalesced): feat f = w*16+lr*4+j -> head 2w+(lr>>1), slot (lr&1)*4+j
  const int head = 2 * w + (lr >> 1), sb = (lr & 1) * 4;
  {
    _Float16* kdst = (_Float16*)kvhk + ((size_t)(b * NH + head) * NSEQ) * 8 + sb;
#pragma unroll
    for (int nt = 0; nt < 4; ++nt) {
      const int tok = a * 64 + nt * 16 + lc;
      f16x4 pk4;
      pk4[0]=(_Float16)acck[nt][0]; pk4[1]=(_Float16)acck[nt][1];
      pk4[2]=(_Float16)acck[nt][2]; pk4[3]=(_Float16)acck[nt][3];
      *(f16x4*)(kdst + (size_t)tok * 8) = pk4;
    }
  }
  __syncthreads(); // all xb GEMM reads done -> overlay vtile on xb

  _Float16 (*vtile)[72] = (_Float16(*)[72])xb; // 64x72 f16 = 9216B, 16B rows
  {
    const int f0 = w * 16 + lr * 4;
#pragma unroll
    for (int nt = 0; nt < 4; ++nt) {
      const int tok = nt * 16 + lc;
#pragma unroll
      for (int j = 0; j < 4; ++j) vtile[f0 + j][tok] = (_Float16)accv[nt][j];
    }
  }
  if (t < 64) marr[t] = red[0][t] + red[1][t] + red[2][t] + red[3][t];
  __syncthreads();

  // coalesced V^T stores: thread -> row r (feat), piece p (16 tokens = 32B)
  {
    const int r = t >> 2, p = t & 3;
    _Float16* drow = (_Float16*)vt +
        ((size_t)(b * NH + (r >> 3)) * 9 + (r & 7)) * NSEQ + a * 64 + p * 16;
    f16x8 v0 = *(const f16x8*)&vtile[r][p * 16];
    f16x8 v1 = *(const f16x8*)&vtile[r][p * 16 + 8];
    *(f16x8*)drow = v0;
    *(f16x8*)(drow + 8) = v1;
  }
  // agent via mean-first (linearity of pooling), f32 math -> f16 store
  if (t < 64) {
    const float4* wqr = (const float4*)(Wq + (size_t)t * NDIM);
    const float4* mm = (const float4*)marr;
    float s0 = 0.f;
#pragma unroll
    for (int i = 0; i < 16; ++i) {
      float4 wv4 = wqr[i], m4 = mm[i];
      s0 += wv4.x * m4.x + wv4.y * m4.y + wv4.z * m4.z + wv4.w * m4.w;
    }
    const float val = s0 * (kScale * kLog2e / 64.f);
    ((_Float16*)agf16)[(((size_t)b * NH + (t >> 3)) * NAG + a) * 8 + (t & 7)] =
        (_Float16)val;
  }
}

// ---------------------------------------------------------------------------
// Kernel B: stage-0 attention via MFMA, with next-chunk register prefetch.
// grid (8, 32, SPLIT), block 256 (4 waves). Per-z partials -> pvs_z.
// ---------------------------------------------------------------------------
__global__ __launch_bounds__(256, 4) void stage0_kernel(
    const us* __restrict__ kvhk, const us* __restrict__ vt,
    const us* __restrict__ agf16, float* __restrict__ pvs_z) {
  __shared__ _Float16 pshuf[4][4][16][40]; // [wave][agtile][agent][tok32 pad] 20KB
  __shared__ float redS[64][12];           // 3KB
  const int h = blockIdx.x, b = blockIdx.y, z = blockIdx.z;
  const int t = threadIdx.x, l = t & 63, w = t >> 6;
  for (int i = t; i < 64 * 12; i += 256) (&redS[0][0])[i] = 0.f;

  const int lg = l >> 4, lm = l & 15;
  const size_t bh = (size_t)b * NH + h;
  const us* kb = kvhk + bh * ((size_t)NSEQ * 8);
  const us* vb = vt + bh * ((size_t)9 * NSEQ);
  const us* ab = agf16 + bh * (NAG * 8);

  // B_A frags (loop-invariant): agent cols; lg>0 zeroed (kills pad dims)
  f16x8 ba[4];
#pragma unroll
  for (int at = 0; at < 4; ++at) {
    f16x8 v = (f16x8)(_Float16)0.0f;
    if (lg == 0) {
      int row = at * 16 + lm; if (row > 48) row = 48;
      v = *(const f16x8*)(ab + row * 8);
    }
    ba[at] = v;
  }
  const us* vrow = vb + (size_t)((lm > 8) ? 8 : lm) * NSEQ + lg * 8;

  f32x4 accPV[4];
#pragma unroll
  for (int i = 0; i < 4; ++i) accPV[i] = (f32x4){0.f, 0.f, 0.f, 0.f};

  _Float16* ps = &pshuf[w][0][0][0];
  const int iw = z * 4 + w;
  __syncthreads(); // redS zero visible before any epilogue atomics

  f16x8 aK0, aK1, bV;
  aK0 = *(const f16x8*)(kb + ((size_t)iw * 32 + lm) * 8 + lg * 8);
  aK1 = *(const f16x8*)(kb + ((size_t)iw * 32 + 16 + lm) * 8 + lg * 8);
  bV  = *(const f16x8*)(vrow + iw * 32);

  for (int c = iw; c < 98; c += 16) {
    f16x8 nK0, nK1, nV;
    const int cn = c + 16;
    if (cn < 98) { // prefetch next chunk (covers L2 latency under MFMAs)
      nK0 = *(const f16x8*)(kb + ((size_t)cn * 32 + lm) * 8 + lg * 8);
      nK1 = *(const f16x8*)(kb + ((size_t)cn * 32 + 16 + lm) * 8 + lg * 8);
      nV  = *(const f16x8*)(vrow + cn * 32);
    }
#pragma unroll
    for (int at = 0; at < 4; ++at) {
      f32x4 s0 = __builtin_amdgcn_mfma_f32_16x16x32_f16(
          aK0, ba[at], (f32x4){0.f, 0.f, 0.f, 0.f}, 0, 0, 0);
      f32x4 s1 = __builtin_amdgcn_mfma_f32_16x16x32_f16(
          aK1, ba[at], (f32x4){0.f, 0.f, 0.f, 0.f}, 0, 0, 0);
      unsigned p00 = pk2(fexp2(s0[0]), fexp2(s0[1]));
      unsigned p01 = pk2(fexp2(s0[2]), fexp2(s0[3]));
      unsigned p10 = pk2(fexp2(s1[0]), fexp2(s1[1]));
      unsigned p11 = pk2(fexp2(s1[2]), fexp2(s1[3]));
      unsigned long long q0 = ((unsigned long long)p01 << 32) | p00;
      unsigned long long q1 = ((unsigned long long)p11 << 32) | p10;
      _Float16* prow = ps + (size_t)(at * 16 + lm) * 40;
      *(unsigned long long*)(prow + lg * 4) = q0;
      *(unsigned long long*)(prow + 16 + lg * 4) = q1;
    }
#pragma unroll
    for (int at = 0; at < 4; ++at) {
      f16x8 aP = *(const f16x8*)(ps + (size_t)(at * 16 + lm) * 40 + lg * 8);
      accPV[at] = __builtin_amdgcn_mfma_f32_16x16x32_f16(aP, bV, accPV[at], 0, 0, 0);
    }
    aK0 = nK0; aK1 = nK1; bV = nV;
  }

  // epilogue: lane holds feat col lm (<9 used), agents at*16 + lg*4 + j
  if (lm < 9) {
#pragma unroll
    for (int at = 0; at < 4; ++at)
#pragma unroll
      for (int jj = 0; jj < 4; ++jj) {
        const int ag = at * 16 + lg * 4 + jj;
        if (ag < NAG) atomicAdd(&redS[ag][lm], accPV[at][jj]);
      }
  }
  __syncthreads();
  float* pz = pvs_z + ((size_t)z * (NB * NH) + bh) * (NAG * 12);
  for (int i = t; i < NAG * 9; i += 256) {
    pz[(i / 9) * 12 + (i % 9)] = redS[i / 9][i % 9];
  }
}

// ---------------------------------------------------------------------------
// Kernel D: finalize PV table ONCE per (b,h): z-sum + rcp, emit TRANSPOSED
// pvtF[b,h][feat 16][agent 64] f16; feat 8 = ones row (denominator column),
// feats 9-15 and agents 49-63 zero (pad-kill for stage1 PV MFMA).
// grid (NH, NB), 64 threads.
// ---------------------------------------------------------------------------
__global__ __launch_bounds__(64) void aofin_kernel(
    const float* __restrict__ pvs_z, us* __restrict__ pvtF) {
  const int h = blockIdx.x, b = blockIdx.y, t = threadIdx.x;
  const size_t bh = (size_t)b * NH + h;
  f32x4 pv0 = (f32x4){0.f,0.f,0.f,0.f}, pv1 = (f32x4){0.f,0.f,0.f,0.f};
  float den = 0.f;
  if (t < NAG) {
#pragma unroll
    for (int zz = 0; zz < SPLIT; ++zz) {
      const float* pp = pvs_z + (((size_t)zz * (NB * NH) + bh) * NAG + t) * 12;
      pv0 += *(const f32x4*)pp;
      pv1 += *(const f32x4*)(pp + 4);
      den += pp[8];
    }
  }
  float inv = (t < NAG) ? frcp(den) : 0.f;
  us* col = pvtF + bh * 1024 + t;
  _Float16 v0 = (_Float16)(pv0[0]*inv), v1 = (_Float16)(pv0[1]*inv);
  _Float16 v2 = (_Float16)(pv0[2]*inv), v3 = (_Float16)(pv0[3]*inv);
  _Float16 v4 = (_Float16)(pv1[0]*inv), v5 = (_Float16)(pv1[1]*inv);
  _Float16 v6 = (_Float16)(pv1[2]*inv), v7 = (_Float16)(pv1[3]*inv);
  col[0*64] = __builtin_bit_cast(us, v0); col[1*64] = __builtin_bit_cast(us, v1);
  col[2*64] = __builtin_bit_cast(us, v2); col[3*64] = __builtin_bit_cast(us, v3);
  col[4*64] = __builtin_bit_cast(us, v4); col[5*64] = __builtin_bit_cast(us, v5);
  col[6*64] = __builtin_bit_cast(us, v6); col[7*64] = __builtin_bit_cast(us, v7);
  col[8*64] = (t < NAG) ? (us)0x3C00 : (us)0;
#pragma unroll
  for (int f = 9; f < 16; ++f) col[f*64] = 0;
}

// ---------------------------------------------------------------------------
// Kernel C: stage-1 attention (MFMA, mirrors stage0) + output linear, fused.
// grid (49, 32), block 512 (8 waves; wave w = head w). Agent tables live in
// MFMA fragments (loaded ONCE per wave) -- no per-token LDS table reads.
// Per 16-token group: 4 S-MFMA -> exp2/pack -> swizzled pW -> 2 PV-MFMA;
// denominator = PV output col 8 (ones row); catL written into qcat col-slice.
// ---------------------------------------------------------------------------
__global__ __launch_bounds__(512, 6) void stage1_out_kernel(
    const float* __restrict__ x1, const __bf16* __restrict__ wq,
    const us* __restrict__ agf16, const us* __restrict__ pvtF,
    const __bf16* __restrict__ wo, const float* __restrict__ bo,
    float* __restrict__ out) {
  __shared__ __align__(16) __bf16 xa[64][72];      // 9216
  __shared__ __align__(16) us qcat[64][72];        // 9216 (q f16, then catL bf16)
  __shared__ __align__(16) _Float16 pW[8][16][72]; // 18432 per-wave P tiles
  const int tile = blockIdx.x, b = blockIdx.y;
  const int t = threadIdx.x, tokl = t & 63, h = t >> 6;
  const int w = h, lane = t & 63, lr = (lane >> 4) & 3, lc = lane & 15;
  const int mtile = w & 3, thalf = w >> 2;
  const size_t bh = (size_t)b * NH + w;

  // prefetch q-weight frags (overlap with staging)
  bf16x8 wqf0 = *(const bf16x8*)(wq + (size_t)(mtile * 16 + lc) * NDIM + lr * 8);
  bf16x8 wqf1 = *(const bf16x8*)(wq + (size_t)(mtile * 16 + lc) * NDIM + 32 + lr * 8);

  // agent-table MFMA frags (ONCE per wave, from L2):
  // ba[at]: A[m=agent at*16+lc][k=dim] (lr==0 real dims 0..7, else 0)
  f16x8 ba[4];
#pragma unroll
  for (int at = 0; at < 4; ++at) {
    f16x8 v = (f16x8)(_Float16)0.0f;
    if (lr == 0) {
      int row = at * 16 + lc; if (row > 48) row = 48;
      v = *(const f16x8*)(agf16 + bh * (NAG * 8) + row * 8);
    }
    ba[at] = v;
  }
  // pvB: B[k=agent][n=feat lc]; pvtF[feat][agent] rows contiguous
  const us* pvb = pvtF + bh * 1024;
  f16x8 pvB0 = *(const f16x8*)(pvb + lc * 64 + lr * 8);
  f16x8 pvB1 = *(const f16x8*)(pvb + lc * 64 + 32 + lr * 8);

  // stage x1 tile bf16 (thread: token tokl, cols h*8..h*8+7)
  {
    const float4* src = (const float4*)(x1 + ((size_t)b * NSEQ + tile * 64 + tokl) * NDIM + h * 8);
    float4 v0 = src[0], v1 = src[1];
    bf16x8 p;
    p[0]=(__bf16)v0.x; p[1]=(__bf16)v0.y; p[2]=(__bf16)v0.z; p[3]=(__bf16)v0.w;
    p[4]=(__bf16)v1.x; p[5]=(__bf16)v1.y; p[6]=(__bf16)v1.z; p[7]=(__bf16)v1.w;
    *(bf16x8*)&xa[tokl][h * 8] = p;
  }
  __syncthreads();

  // q^T = Wq @ x1^T -> qcat as f16 (all 64 feat cols)
  {
    f32x4 aq[2];
    aq[0] = (f32x4){0.f,0.f,0.f,0.f}; aq[1] = (f32x4){0.f,0.f,0.f,0.f};
#pragma unroll
    for (int nt = 0; nt < 2; ++nt) {
      bf16x8 bx0 = *(const bf16x8*)&xa[thalf * 32 + nt * 16 + lc][lr * 8];
      bf16x8 bx1 = *(const bf16x8*)&xa[thalf * 32 + nt * 16 + lc][32 + lr * 8];
      aq[nt] = __builtin_amdgcn_mfma_f32_16x16x32_bf16(wqf0, bx0, aq[nt], 0, 0, 0);
      aq[nt] = __builtin_amdgcn_mfma_f32_16x16x32_bf16(wqf1, bx1, aq[nt], 0, 0, 0);
    }
#pragma unroll
    for (int nt = 0; nt < 2; ++nt) {
      f16x4 pk;
      pk[0]=(_Float16)aq[nt][0]; pk[1]=(_Float16)aq[nt][1];
      pk[2]=(_Float16)aq[nt][2]; pk[3]=(_Float16)aq[nt][3];
      *(f16x4*)&qcat[thalf * 32 + nt * 16 + lc][mtile * 16 + lr * 4] = pk;
    }
  }
  __syncthreads();

  // ---- stage-1 attention via MFMA; wave w handles head w only ----
  // No cross-wave hazards: wave w reads q cols w*8.. and writes catL cols w*8..
  {
    _Float16* psw = &pW[w][0][0];
    const int swz = (lc & 7) << 4; // XOR swizzle (byte units) vs bank conflicts
#pragma unroll 1
    for (int g = 0; g < 4; ++g) {
      // B q-frag: lane lc = token col; lr>0 garbage killed by ba zeros
      f16x8 qf = *(const f16x8*)&qcat[g * 16 + lc][w * 8];
      // S = mfma(agents, q): C col = token lc, row = agent lr*4+reg (per tile)
#pragma unroll
      for (int at = 0; at < 4; ++at) {
        f32x4 sc = __builtin_amdgcn_mfma_f32_16x16x32_f16(
            ba[at], qf, (f32x4){0.f, 0.f, 0.f, 0.f}, 0, 0, 0);
        unsigned u0 = pk2(fexp2(sc[0]), fexp2(sc[1]));
        unsigned u1 = pk2(fexp2(sc[2]), fexp2(sc[3]));
        unsigned long long q = ((unsigned long long)u1 << 32) | u0;
        *(unsigned long long*)((char*)psw + lc * 144 + (((at * 32) | (lr * 8)) ^ swz)) = q;
      }
      // P A-frags: lane lc = token row, k = agents lr*8.. (same-wave LDS)
      f16x8 pA0 = *(const f16x8*)((char*)psw + lc * 144 + ((lr * 16) ^ swz));
      f16x8 pA1 = *(const f16x8*)((char*)psw + lc * 144 + ((64 + lr * 16) ^ swz));
      f32x4 pv = __builtin_amdgcn_mfma_f32_16x16x32_f16(pA0, pvB0,
                   (f32x4){0.f, 0.f, 0.f, 0.f}, 0, 0, 0);
      pv = __builtin_amdgcn_mfma_f32_16x16x32_f16(pA1, pvB1, pv, 0, 0, 0);
      // C: col = feat lc (8 = denominator), row = token lr*4+j
#pragma unroll
      for (int j = 0; j < 4; ++j) {
        float den = __shfl(pv[j], (lane & 48) | 8);
        if (lc < 8) {
          float val = pv[j] * frcp(den);
          *(__bf16*)&qcat[g * 16 + lr * 4 + j][w * 8 + lc] = (__bf16)val;
        }
      }
    }
  }
  // load Wo frags + bias late (issue under the barrier wait)
  bf16x8 wof[4];
#pragma unroll
  for (int ks = 0; ks < 4; ++ks)
    wof[ks] = *(const bf16x8*)(wo + (size_t)(w * 16 + lc) * 128 + ks * 32 + lr * 8);
  f32x4 bv = *(const f32x4*)(bo + w * 16 + lr * 4);
  __syncthreads();

  // out^T = Wo @ [catL|xa]^T; direct stores (lane: 4 consecutive feats of 1 tok)
  {
    f32x4 acc[4];
#pragma unroll
    for (int i = 0; i < 4; ++i) acc[i] = (f32x4){0.f,0.f,0.f,0.f};
#pragma unroll
    for (int ks = 0; ks < 4; ++ks) {
#pragma unroll
      for (int nt = 0; nt < 4; ++nt) {
        bf16x8 bx = (ks < 2) ? *(const bf16x8*)&qcat[nt * 16 + lc][ks * 32 + lr * 8]
                             : *(const bf16x8*)&xa[nt * 16 + lc][(ks - 2) * 32 + lr * 8];
        acc[nt] = __builtin_amdgcn_mfma_f32_16x16x32_bf16(wof[ks], bx, acc[nt], 0, 0, 0);
      }
    }
#pragma unroll
    for (int nt = 0; nt < 4; ++nt) {
      f32x4 v = acc[nt] + bv;
      float* dst = out + ((size_t)b * NSEQ + tile * 64 + nt * 16 + lc) * 128 + w * 16 + lr * 4;
      *(f32x4*)dst = v;
    }
  }
}

extern "C" void kernel_launch(void* const* d_in, const int* in_sizes, int n_in,
                              void* d_out, int out_size, void* d_ws, size_t ws_size,
                              hipStream_t stream) {
  (void)in_sizes; (void)n_in; (void)out_size; (void)ws_size;
  const float* x1 = (const float*)d_in[0];
  const float* x2 = (const float*)d_in[1];
  const float* Wq = (const float*)d_in[2];
  const float* Wk = (const float*)d_in[3];
  const float* Wv = (const float*)d_in[4];
  const float* Wo = (const float*)d_in[5];
  const float* bo = (const float*)d_in[6];
  float* out = (float*)d_out;

  us* vt = (us*)d_ws;                                      // 32*8*9*3136 f16 = 14.45MB
  us* kvhk = vt + (size_t)NB * NH * 9 * NSEQ;              // 32*8*3136*8 f16 (+32 pad)
  us* agf16 = kvhk + (size_t)NB * NH * NSEQ * 8 + 32;      // 100352 f16
  float* pvs_z = (float*)(agf16 + (size_t)NB * NH * NAG * 8);
  us* pvtF = (us*)(pvs_z + (size_t)SPLIT * NB * NH * NAG * 12); // 256*1024 f16
  __bf16* wq_bf = (__bf16*)(pvtF + (size_t)NB * NH * 1024);
  __bf16* wk_bf = wq_bf + 4096;
  __bf16* wv_bf = wk_bf + 4096;
  __bf16* wo_bf = wv_bf + 4096;
  // total ws ~= 30.5 MB

  prep_kernel<<<dim3(64), 256, 0, stream>>>(Wq, Wk, Wv, Wo, wq_bf, wk_bf, wv_bf,
                                            wo_bf, kvhk, vt);
  qkv_agent_kernel<<<dim3(NAG, NB), 256, 0, stream>>>(x1, x2, Wq, wk_bf, wv_bf,
                                                      kvhk, vt, agf16);
  stage0_kernel<<<dim3(NH, NB, SPLIT), 256, 0, stream>>>(kvhk, vt, agf16, pvs_z);
  aofin_kernel<<<dim3(NH, NB), 64, 0, stream>>>(pvs_z, pvtF);
  stage1_out_kernel<<<dim3(NAG, NB), 512, 0, stream>>>(x1, wq_bf, agf16, pvtF,
                                                       wo_bf, bo, out);
}